// Round 1
// baseline (899.698 us; speedup 1.0000x reference)
//
#include <hip/hip_runtime.h>
#include <hip/hip_bf16.h>

#define NN 3600
#define MP 3712          // 29*128 padded rows
#define NHID 512
#define NH (3600*512)
#define EE 230400

typedef __hip_bfloat16 bf16;
typedef __bf16 bf16x8 __attribute__((ext_vector_type(8)));
typedef float f32x4 __attribute__((ext_vector_type(4)));

typedef __attribute__((address_space(1))) void as1v;
typedef __attribute__((address_space(3))) void as3v;

__device__ __forceinline__ void glds16(void* lds, const void* g) {
  __builtin_amdgcn_global_load_lds((as1v*)(void*)g, (as3v*)lds, 16, 0, 0);
}

// ---------------- GEMM: C(MPxN f32) = A(MPxKp bf16, row-major) * B(NxKp bf16, row-major)^T
// 128x128 tile, BK=32, 4 waves, 4x4 16x16x32 frags per wave (m97 structure)
__global__ __launch_bounds__(256) void gemm_bt(const bf16* __restrict__ A,
                                               const bf16* __restrict__ B,
                                               float* __restrict__ C,
                                               int Kp, int ldc)
{
  __shared__ alignas(16) char smem[16384];   // As[128][32] | Bs[128][32] bf16
  const int t = threadIdx.x, w = t >> 6, l = t & 63;
  const int mbase = blockIdx.y << 7, nbase = blockIdx.x << 7;
  const size_t ldb = (size_t)Kp * 2;          // row stride bytes
  const char* gA = (const char*)A + (size_t)(mbase + w*16 + (l>>2)) * ldb + (size_t)((l&3)*16);
  const char* gB = (const char*)B + (size_t)(nbase + w*16 + (l>>2)) * ldb + (size_t)((l&3)*16);
  char* lA = smem + w*1024;
  char* lB = smem + 8192 + w*1024;
  const int wm = (w>>1)*64, wn = (w&1)*64;
  const int aoff = (wm + (l&15))*64 + (l>>4)*16;
  const int boff = 8192 + (wn + (l&15))*64 + (l>>4)*16;
  f32x4 acc[4][4] = {};
  const int steps = Kp >> 5;
  const size_t chunk = ldb * 64;
  for (int kt = 0; kt < steps; ++kt) {
    const size_t ko = (size_t)kt * 64;
    __syncthreads();                       // prev compute done before overwrite
    glds16(lA,        gA + ko);
    glds16(lA + 4096, gA + ko + chunk);
    glds16(lB,        gB + ko);
    glds16(lB + 4096, gB + ko + chunk);
    __syncthreads();                       // drains vmcnt -> LDS ready
    bf16x8 av[4], bv[4];
#pragma unroll
    for (int mi = 0; mi < 4; ++mi) av[mi] = *(const bf16x8*)(smem + aoff + mi*1024);
#pragma unroll
    for (int ni = 0; ni < 4; ++ni) bv[ni] = *(const bf16x8*)(smem + boff + ni*1024);
#pragma unroll
    for (int mi = 0; mi < 4; ++mi)
#pragma unroll
      for (int ni = 0; ni < 4; ++ni)
        acc[mi][ni] = __builtin_amdgcn_mfma_f32_16x16x32_bf16(av[mi], bv[ni], acc[mi][ni], 0, 0, 0);
  }
  // C/D layout: col = lane&15, row = (lane>>4)*4 + reg  [m89 verified]
  const int crow = mbase + wm + ((l>>4)<<2);
  const int ccol = nbase + wn + (l&15);
#pragma unroll
  for (int mi = 0; mi < 4; ++mi)
#pragma unroll
    for (int ni = 0; ni < 4; ++ni) {
      float* cp = C + (size_t)(crow + mi*16)*ldc + (ccol + ni*16);
#pragma unroll
      for (int j = 0; j < 4; ++j) cp[(size_t)j*ldc] = acc[mi][ni][j];
    }
}

// ---------------- packing kernels ----------------
__global__ void pack_B(const float* __restrict__ wih, const float* __restrict__ whh,
                       bf16* __restrict__ dst, int kx, int Kp)
{
  int col = blockIdx.x*256 + threadIdx.x;
  int row = blockIdx.y;
  if (col >= Kp) return;
  float v = 0.f;
  if (col < kx) v = wih[(size_t)row*kx + col];
  else if (col < kx + 512) v = whh[(size_t)row*512 + (col - kx)];
  dst[(size_t)row*Kp + col] = __float2bfloat16(v);
}

__global__ void pack_BT(const float* __restrict__ W, bf16* __restrict__ dst, int Nc, int K)
{
  int k = blockIdx.x*256 + threadIdx.x;
  int n = blockIdx.y;
  if (k >= K) return;
  dst[(size_t)n*K + k] = __float2bfloat16(W[(size_t)k*Nc + n]);
}

__global__ void pack_A0(const float* __restrict__ x, const float* __restrict__ h0,
                        bf16* __restrict__ a0f, bf16* __restrict__ a0b)
{
  int col = blockIdx.x*256 + threadIdx.x;  // [0,1120)
  int n = blockIdx.y;                      // [0,3712)
  if (col >= 1120) return;
  float vf = 0.f, vb = 0.f;
  if (n < NN) {
    if (col < 588) { vf = vb = x[(size_t)n*972 + col]; }
    else if (col < 1100) {
      vf = h0[(size_t)n*512 + (col-588)];
      vb = h0[(size_t)NH + (size_t)n*512 + (col-588)];
    }
  }
  a0f[(size_t)n*1120 + col] = __float2bfloat16(vf);
  a0b[(size_t)n*1120 + col] = __float2bfloat16(vb);
}

__global__ void pack_A1h(const float* __restrict__ h2, const float* __restrict__ h3,
                         bf16* __restrict__ a1f, bf16* __restrict__ a1b)
{
  int j = blockIdx.x*256 + threadIdx.x;    // [0,512)
  int n = blockIdx.y;
  if (j >= 512) return;
  float vf = (n < NN) ? h2[(size_t)n*512 + j] : 0.f;
  float vb = (n < NN) ? h3[(size_t)n*512 + j] : 0.f;
  a1f[(size_t)n*1536 + 1024 + j] = __float2bfloat16(vf);
  a1b[(size_t)n*1536 + 1024 + j] = __float2bfloat16(vb);
}

__global__ void pack_prot(const float* __restrict__ x, bf16* __restrict__ afeat)
{
  int k = blockIdx.x*256 + threadIdx.x;    // [0,384)
  int n = blockIdx.y;
  if (k >= 384) return;
  float v = (n < NN) ? x[(size_t)n*972 + 588 + k] : 0.f;
  afeat[(size_t)n*1408 + k] = __float2bfloat16(v);
}

// ---------------- degree / norm ----------------
__global__ void deg_count(const int* __restrict__ ecols, int* __restrict__ deg)
{
  int e = blockIdx.x*256 + threadIdx.x;
  if (e < EE) atomicAdd(&deg[ecols[e]], 1);
}

__global__ void calc_dinv(const int* __restrict__ deg, float* __restrict__ dinv)
{
  int n = blockIdx.x*256 + threadIdx.x;
  if (n < NN) dinv[n] = 1.0f / sqrtf((float)(deg[n] + 1));   // +1 self loop
}

// ---------------- LSTM gate fuse ----------------
__device__ __forceinline__ float sigm(float v) { return 1.0f / (1.0f + expf(-v)); }

__global__ void lstm_gate(const float* __restrict__ g, const float* __restrict__ c0,
                          const float* __restrict__ bih, const float* __restrict__ bhh,
                          bf16* __restrict__ d1, bf16* __restrict__ d2,
                          int ld, float scale)
{
  int idx = blockIdx.x*256 + threadIdx.x;  // exactly 3600*512 threads
  int n = idx >> 9, j = idx & 511;
  size_t gb = (size_t)n * 2048;
  float gi = g[gb + j]        + bih[j]        + bhh[j];
  float gf = g[gb + 512 + j]  + bih[512+j]    + bhh[512+j];
  float gg = g[gb + 1024 + j] + bih[1024+j]   + bhh[1024+j];
  float go = g[gb + 1536 + j] + bih[1536+j]   + bhh[1536+j];
  float c2 = sigm(gf) * c0[(size_t)n*512 + j] + sigm(gi) * tanhf(gg);
  float h = sigm(go) * tanhf(c2) * scale;
  bf16 hb = __float2bfloat16(h);
  d1[(size_t)n*ld + j] = hb;
  if (d2) d2[(size_t)n*ld + j] = hb;
}

// ---------------- GCN helpers ----------------
__global__ void init_bias(float* __restrict__ out, const float* __restrict__ b,
                          int mask, int total)
{
  int idx = blockIdx.x*256 + threadIdx.x;
  if (idx < total) out[idx] = b[idx & mask];
}

__global__ void relu_bf(const float* __restrict__ src, bf16* __restrict__ dst, int total)
{
  int idx = blockIdx.x*256 + threadIdx.x;
  if (idx < total) dst[idx] = __float2bfloat16(fmaxf(src[idx], 0.f));
}

__global__ void gcn_scatter(const float* __restrict__ xw, const int* __restrict__ er,
                            const int* __restrict__ ec, const float* __restrict__ dinv,
                            float* __restrict__ out, int F)
{
  int gw = (blockIdx.x * blockDim.x + threadIdx.x) >> 6;  // one wave per edge
  int l = threadIdx.x & 63;
  if (gw >= EE + NN) return;
  int r, c;
  if (gw < EE) { r = er[gw]; c = ec[gw]; } else { r = gw - EE; c = r; }
  float wgt = dinv[r] * dinv[c];
  const float* src = xw + (size_t)r * F;
  float* dst = out + (size_t)c * F;
  for (int f = l; f < F; f += 64) atomicAdd(&dst[f], src[f] * wgt);
}

// ---------------- workspace layout (bytes) ----------------
#define OFF_DEG   ((size_t)0)
#define OFF_DINV  ((size_t)16384)
#define OFF_B0F   ((size_t)32768)
#define OFF_B0B   ((size_t)4620288)
#define OFF_B1F   ((size_t)9207808)
#define OFF_B1B   ((size_t)15499264)
#define OFF_BW1   ((size_t)21790720)
#define OFF_BW2   ((size_t)23232512)
#define OFF_A0F   ((size_t)23494656)
#define OFF_A0B   ((size_t)31809536)
#define OFF_A1F   ((size_t)40124416)
#define OFF_A1B   ((size_t)51527680)
#define OFF_G     ((size_t)62930944)
// overlays (regions dead by the time these are live):
#define OFF_AFEAT OFF_A0F                      // feat over A0 (A0 dead after gemm0b)
#define OFF_XW1   OFF_G                        // GCN scratch over g (g dead after gate1b)
#define OFF_OUT1  ((size_t)70533120)
#define OFF_H1    ((size_t)78135296)
#define OFF_XW2   ((size_t)81936384)
// total ws needed: 93,339,648 bytes

extern "C" void kernel_launch(void* const* d_in, const int* in_sizes, int n_in,
                              void* d_out, int out_size, void* d_ws, size_t ws_size,
                              hipStream_t stream)
{
  const float* x    = (const float*)d_in[0];
  const int*   ei   = (const int*)d_in[1];
  const float* h0   = (const float*)d_in[2];
  const float* c0   = (const float*)d_in[3];
  const float* wih0f = (const float*)d_in[4];
  const float* whh0f = (const float*)d_in[5];
  const float* bih0f = (const float*)d_in[6];
  const float* bhh0f = (const float*)d_in[7];
  const float* wih0b = (const float*)d_in[8];
  const float* whh0b = (const float*)d_in[9];
  const float* bih0b = (const float*)d_in[10];
  const float* bhh0b = (const float*)d_in[11];
  const float* wih1f = (const float*)d_in[12];
  const float* whh1f = (const float*)d_in[13];
  const float* bih1f = (const float*)d_in[14];
  const float* bhh1f = (const float*)d_in[15];
  const float* wih1b = (const float*)d_in[16];
  const float* whh1b = (const float*)d_in[17];
  const float* bih1b = (const float*)d_in[18];
  const float* bhh1b = (const float*)d_in[19];
  const float* W1 = (const float*)d_in[20];
  const float* b1 = (const float*)d_in[21];
  const float* W2 = (const float*)d_in[22];
  const float* b2 = (const float*)d_in[23];

  char* ws = (char*)d_ws;
  int*   deg  = (int*)(ws + OFF_DEG);
  float* dinv = (float*)(ws + OFF_DINV);
  bf16* B0f = (bf16*)(ws + OFF_B0F);
  bf16* B0b = (bf16*)(ws + OFF_B0B);
  bf16* B1f = (bf16*)(ws + OFF_B1F);
  bf16* B1b = (bf16*)(ws + OFF_B1B);
  bf16* BW1 = (bf16*)(ws + OFF_BW1);
  bf16* BW2 = (bf16*)(ws + OFF_BW2);
  bf16* A0f = (bf16*)(ws + OFF_A0F);
  bf16* A0b = (bf16*)(ws + OFF_A0B);
  bf16* A1f = (bf16*)(ws + OFF_A1F);
  bf16* A1b = (bf16*)(ws + OFF_A1B);
  bf16* Afeat = (bf16*)(ws + OFF_AFEAT);
  float* g    = (float*)(ws + OFF_G);
  float* xw1  = (float*)(ws + OFF_XW1);
  float* out1 = (float*)(ws + OFF_OUT1);
  bf16*  h1bf = (bf16*)(ws + OFF_H1);
  float* xw2  = (float*)(ws + OFF_XW2);
  float* outp = (float*)d_out;

  // degree + norm
  hipMemsetAsync(deg, 0, (size_t)NN*4, stream);
  deg_count<<<dim3((EE+255)/256), 256, 0, stream>>>(ei + EE, deg);
  calc_dinv<<<dim3(15), 256, 0, stream>>>(deg, dinv);

  // weight packing (bf16, zero-padded K)
  pack_B<<<dim3(5, 2048), 256, 0, stream>>>(wih0f, whh0f, B0f, 588, 1120);
  pack_B<<<dim3(5, 2048), 256, 0, stream>>>(wih0b, whh0b, B0b, 588, 1120);
  pack_B<<<dim3(6, 2048), 256, 0, stream>>>(wih1f, whh1f, B1f, 1024, 1536);
  pack_B<<<dim3(6, 2048), 256, 0, stream>>>(wih1b, whh1b, B1b, 1024, 1536);
  pack_BT<<<dim3(6, 512), 256, 0, stream>>>(W1, BW1, 512, 1408);
  pack_BT<<<dim3(2, 256), 256, 0, stream>>>(W2, BW2, 256, 512);

  // activations packing
  pack_A0<<<dim3(5, MP), 256, 0, stream>>>(x, h0, A0f, A0b);
  pack_A1h<<<dim3(2, MP), 256, 0, stream>>>(h0 + (size_t)2*NH, h0 + (size_t)3*NH, A1f, A1b);

  // LSTM layer 0
  gemm_bt<<<dim3(16, 29), 256, 0, stream>>>(A0f, B0f, g, 1120, 2048);
  lstm_gate<<<dim3(7200), 256, 0, stream>>>(g, c0 + (size_t)0*NH, bih0f, bhh0f,
                                            A1f, A1b, 1536, 1.0f);
  gemm_bt<<<dim3(16, 29), 256, 0, stream>>>(A0b, B0b, g, 1120, 2048);
  lstm_gate<<<dim3(7200), 256, 0, stream>>>(g, c0 + (size_t)1*NH, bih0b, bhh0b,
                                            A1f + 512, A1b + 512, 1536, 1.0f);

  // feat: prot part (A0 is dead now; Afeat overlays it)
  pack_prot<<<dim3(2, MP), 256, 0, stream>>>(x, Afeat);

  // LSTM layer 1 (writes x_p/100 into feat)
  gemm_bt<<<dim3(16, 29), 256, 0, stream>>>(A1f, B1f, g, 1536, 2048);
  lstm_gate<<<dim3(7200), 256, 0, stream>>>(g, c0 + (size_t)2*NH, bih1f, bhh1f,
                                            Afeat + 384, nullptr, 1408, 0.01f);
  gemm_bt<<<dim3(16, 29), 256, 0, stream>>>(A1b, B1b, g, 1536, 2048);
  lstm_gate<<<dim3(7200), 256, 0, stream>>>(g, c0 + (size_t)3*NH, bih1b, bhh1b,
                                            Afeat + 896, nullptr, 1408, 0.01f);

  // GCN layer 1 (g region is dead now; xw1/out1/h1bf/xw2 overlay it)
  gemm_bt<<<dim3(4, 29), 256, 0, stream>>>(Afeat, BW1, xw1, 1408, 512);
  init_bias<<<dim3(MP*512/256), 256, 0, stream>>>(out1, b1, 511, MP*512);
  gcn_scatter<<<dim3((EE+NN)/4), 256, 0, stream>>>(xw1, ei, ei + EE, dinv, out1, 512);
  relu_bf<<<dim3(MP*512/256), 256, 0, stream>>>(out1, h1bf, MP*512);

  // GCN layer 2
  gemm_bt<<<dim3(2, 29), 256, 0, stream>>>(h1bf, BW2, xw2, 512, 256);
  init_bias<<<dim3(NN*256/256), 256, 0, stream>>>(outp, b2, 255, NN*256);
  gcn_scatter<<<dim3((EE+NN)/4), 256, 0, stream>>>(xw2, ei, ei + EE, dinv, outp, 256);
}

// Round 2
// 604.440 us; speedup vs baseline: 1.4885x; 1.4885x over previous
//
#include <hip/hip_runtime.h>
#include <hip/hip_bf16.h>

#define NN 3600
#define MP 3712          // 29*128 padded rows
#define KADJ 3616        // 113*32 padded node-count for adjacency K
#define NH (3600*512)
#define EE 230400

typedef __hip_bfloat16 bf16;
typedef __bf16 bf16x8 __attribute__((ext_vector_type(8)));
typedef float f32x4 __attribute__((ext_vector_type(4)));

typedef __attribute__((address_space(1))) void as1v;
typedef __attribute__((address_space(3))) void as3v;

__device__ __forceinline__ void glds16(void* lds, const void* g) {
  __builtin_amdgcn_global_load_lds((as1v*)(void*)g, (as3v*)lds, 16, 0, 0);
}

// ---------------- GEMM: C(M x N f32) = A(M x Kp bf16, row-major) * B(N x Kp bf16, row-major)^T + bias
// 128x128 tile, BK=32, 4 waves, 4x4 16x16x32 frags per wave (m97 structure)
// rows >= Mv are not written (C may be exactly-sized)
__global__ __launch_bounds__(256) void gemm_bt(const bf16* __restrict__ A,
                                               const bf16* __restrict__ B,
                                               float* __restrict__ C,
                                               const float* __restrict__ bias,
                                               int Kp, int ldc, int Mv)
{
  __shared__ alignas(16) char smem[16384];   // As[128][32] | Bs[128][32] bf16
  const int t = threadIdx.x, w = t >> 6, l = t & 63;
  const int mbase = blockIdx.y << 7, nbase = blockIdx.x << 7;
  const size_t ldb = (size_t)Kp * 2;          // row stride bytes
  const char* gA = (const char*)A + (size_t)(mbase + w*16 + (l>>2)) * ldb + (size_t)((l&3)*16);
  const char* gB = (const char*)B + (size_t)(nbase + w*16 + (l>>2)) * ldb + (size_t)((l&3)*16);
  char* lA = smem + w*1024;
  char* lB = smem + 8192 + w*1024;
  const int wm = (w>>1)*64, wn = (w&1)*64;
  const int aoff = (wm + (l&15))*64 + (l>>4)*16;
  const int boff = 8192 + (wn + (l&15))*64 + (l>>4)*16;
  f32x4 acc[4][4] = {};
  const int steps = Kp >> 5;
  const size_t chunk = ldb * 64;
  for (int kt = 0; kt < steps; ++kt) {
    const size_t ko = (size_t)kt * 64;
    __syncthreads();                       // prev compute done before overwrite
    glds16(lA,        gA + ko);
    glds16(lA + 4096, gA + ko + chunk);
    glds16(lB,        gB + ko);
    glds16(lB + 4096, gB + ko + chunk);
    __syncthreads();                       // drains vmcnt -> LDS ready
    bf16x8 av[4], bv[4];
#pragma unroll
    for (int mi = 0; mi < 4; ++mi) av[mi] = *(const bf16x8*)(smem + aoff + mi*1024);
#pragma unroll
    for (int ni = 0; ni < 4; ++ni) bv[ni] = *(const bf16x8*)(smem + boff + ni*1024);
#pragma unroll
    for (int mi = 0; mi < 4; ++mi)
#pragma unroll
      for (int ni = 0; ni < 4; ++ni)
        acc[mi][ni] = __builtin_amdgcn_mfma_f32_16x16x32_bf16(av[mi], bv[ni], acc[mi][ni], 0, 0, 0);
  }
  // C/D layout: col = lane&15, row = (lane>>4)*4 + reg  [m89 verified]
  const int crow = mbase + wm + ((l>>4)<<2);
  const int ccol = nbase + wn + (l&15);
#pragma unroll
  for (int mi = 0; mi < 4; ++mi)
#pragma unroll
    for (int ni = 0; ni < 4; ++ni) {
      const float bv2 = bias ? bias[ccol + ni*16] : 0.f;
      float* cp = C + (size_t)(crow + mi*16)*ldc + (ccol + ni*16);
#pragma unroll
      for (int j = 0; j < 4; ++j) {
        const int r = crow + mi*16 + j;
        if (r < Mv) cp[(size_t)j*ldc] = acc[mi][ni][j] + bv2;
      }
    }
}

// ---------------- packing kernels ----------------
__global__ void pack_B(const float* __restrict__ wih, const float* __restrict__ whh,
                       bf16* __restrict__ dst, int kx, int Kp)
{
  int col = blockIdx.x*256 + threadIdx.x;
  int row = blockIdx.y;
  if (col >= Kp) return;
  float v = 0.f;
  if (col < kx) v = wih[(size_t)row*kx + col];
  else if (col < kx + 512) v = whh[(size_t)row*512 + (col - kx)];
  dst[(size_t)row*Kp + col] = __float2bfloat16(v);
}

__global__ void pack_BT(const float* __restrict__ W, bf16* __restrict__ dst, int Nc, int K)
{
  int k = blockIdx.x*256 + threadIdx.x;
  int n = blockIdx.y;
  if (k >= K) return;
  dst[(size_t)n*K + k] = __float2bfloat16(W[(size_t)k*Nc + n]);
}

__global__ void pack_A0(const float* __restrict__ x, const float* __restrict__ h0,
                        bf16* __restrict__ a0f, bf16* __restrict__ a0b)
{
  int col = blockIdx.x*256 + threadIdx.x;  // [0,1120)
  int n = blockIdx.y;                      // [0,3712)
  if (col >= 1120) return;
  float vf = 0.f, vb = 0.f;
  if (n < NN) {
    if (col < 588) { vf = vb = x[(size_t)n*972 + col]; }
    else if (col < 1100) {
      vf = h0[(size_t)n*512 + (col-588)];
      vb = h0[(size_t)NH + (size_t)n*512 + (col-588)];
    }
  }
  a0f[(size_t)n*1120 + col] = __float2bfloat16(vf);
  a0b[(size_t)n*1120 + col] = __float2bfloat16(vb);
}

__global__ void pack_A1h(const float* __restrict__ h2, const float* __restrict__ h3,
                         bf16* __restrict__ a1f, bf16* __restrict__ a1b)
{
  int j = blockIdx.x*256 + threadIdx.x;    // [0,512)
  int n = blockIdx.y;
  if (j >= 512) return;
  float vf = (n < NN) ? h2[(size_t)n*512 + j] : 0.f;
  float vb = (n < NN) ? h3[(size_t)n*512 + j] : 0.f;
  a1f[(size_t)n*1536 + 1024 + j] = __float2bfloat16(vf);
  a1b[(size_t)n*1536 + 1024 + j] = __float2bfloat16(vb);
}

__global__ void pack_prot(const float* __restrict__ x, bf16* __restrict__ afeat)
{
  int k = blockIdx.x*256 + threadIdx.x;    // [0,384)
  int n = blockIdx.y;
  if (k >= 384) return;
  float v = (n < NN) ? x[(size_t)n*972 + 588 + k] : 0.f;
  afeat[(size_t)n*1408 + k] = __float2bfloat16(v);
}

// ---------------- degree / norm ----------------
__global__ void deg_count(const int* __restrict__ ecols, int* __restrict__ deg)
{
  int e = blockIdx.x*256 + threadIdx.x;
  if (e < EE) atomicAdd(&deg[ecols[e]], 1);
}

__global__ void calc_dinv(const int* __restrict__ deg, float* __restrict__ dinv)
{
  int n = blockIdx.x*256 + threadIdx.x;
  if (n < NN) dinv[n] = 1.0f / sqrtf((float)(deg[n] + 1));   // +1 self loop
}

// ---------------- dense normalized adjacency build ----------------
// AdjF[c][r] += dinv[r]*dinv[c]  (fp32, 3600 x KADJ)
__global__ void adj_scatter(const int* __restrict__ er, const int* __restrict__ ec,
                            const float* __restrict__ dinv, float* __restrict__ adjf)
{
  int e = blockIdx.x*256 + threadIdx.x;
  if (e < EE) {
    int r = er[e], c = ec[e];
    atomicAdd(&adjf[(size_t)c*KADJ + r], dinv[r]*dinv[c]);
  } else if (e < EE + NN) {
    int n = e - EE;
    float d = dinv[n];
    atomicAdd(&adjf[(size_t)n*KADJ + n], d*d);
  }
}

// dst bf16 [R][KADJ]; src fp32 with leading dim lds; zero outside (rv, kv)
__global__ void cvt_bf(const float* __restrict__ src, int lds,
                       bf16* __restrict__ dst, int rv, int kv)
{
  int k = blockIdx.x*256 + threadIdx.x;
  int r = blockIdx.y;
  if (k >= KADJ) return;
  float v = (r < rv && k < kv) ? src[(size_t)r*lds + k] : 0.f;
  dst[(size_t)r*KADJ + k] = __float2bfloat16(v);
}

// ---------------- LSTM gate fuse ----------------
__device__ __forceinline__ float sigm(float v) { return 1.0f / (1.0f + expf(-v)); }

__global__ void lstm_gate(const float* __restrict__ g, const float* __restrict__ c0,
                          const float* __restrict__ bih, const float* __restrict__ bhh,
                          bf16* __restrict__ d1, bf16* __restrict__ d2,
                          int ld, float scale)
{
  int idx = blockIdx.x*256 + threadIdx.x;  // exactly 3600*512 threads
  int n = idx >> 9, j = idx & 511;
  size_t gb = (size_t)n * 2048;
  float gi = g[gb + j]        + bih[j]        + bhh[j];
  float gf = g[gb + 512 + j]  + bih[512+j]    + bhh[512+j];
  float gg = g[gb + 1024 + j] + bih[1024+j]   + bhh[1024+j];
  float go = g[gb + 1536 + j] + bih[1536+j]   + bhh[1536+j];
  float c2 = sigm(gf) * c0[(size_t)n*512 + j] + sigm(gi) * tanhf(gg);
  float h = sigm(go) * tanhf(c2) * scale;
  bf16 hb = __float2bfloat16(h);
  d1[(size_t)n*ld + j] = hb;
  if (d2) d2[(size_t)n*ld + j] = hb;
}

__global__ void relu_bf(const float* __restrict__ src, bf16* __restrict__ dst, int total)
{
  int idx = blockIdx.x*256 + threadIdx.x;
  if (idx < total) dst[idx] = __float2bfloat16(fmaxf(src[idx], 0.f));
}

// ---------------- workspace layout (bytes) ----------------
#define OFF_DEG   ((size_t)0)
#define OFF_DINV  ((size_t)16384)
#define OFF_BW2   ((size_t)32768)      //   262,144 (256 x 512 bf16)
#define OFF_B0F   ((size_t)294912)     // 4,587,520
#define OFF_B0B   ((size_t)4882432)
#define OFF_B1F   ((size_t)9469952)    // 6,291,456
#define OFF_B1B   ((size_t)15761408)
#define OFF_BW1   ((size_t)22052864)   // 1,441,792
#define OFF_A0F   ((size_t)23494656)   // 8,314,880
#define OFF_A0B   ((size_t)31809536)   // -> 40,124,416
#define OFF_A1F   ((size_t)40124416)   // 11,403,264
#define OFF_A1B   ((size_t)51527680)   // -> 62,930,944
#define OFF_G     ((size_t)62930944)   // 30,408,704 -> 93,339,648
// ---- overlays (regions dead by the time these are live) ----
#define OFF_AFEAT OFF_A0F              // 10,452,992 -> 33,947,648 (A0 dead)
#define OFF_ADJF  ((size_t)40124416)   // 52,070,400 -> 92,194,816 (A1/g dead after LSTM)
#define OFF_XWT1F ((size_t)294912)     // 7,602,176  (B0 dead)
#define OFF_XWT1B ((size_t)7897088)    // 3,702,784  (B0b/B1f dead)
#define OFF_ADJB  ((size_t)11599872)   // 26,845,184 -> 38,445,056 (B1/BW1/Afeat dead)
#define OFF_OUT1  ((size_t)40124416)   // 7,602,176  (AdjF dead after cvt)
#define OFF_H1    ((size_t)47726592)   // 3,801,088
#define OFF_XWT2F ((size_t)51527680)   // 3,801,088
#define OFF_XWT2B ((size_t)55328768)   // 1,851,392 -> 57,180,160
// total ws needed: 93,339,648 bytes (same as round 0, known OK)

extern "C" void kernel_launch(void* const* d_in, const int* in_sizes, int n_in,
                              void* d_out, int out_size, void* d_ws, size_t ws_size,
                              hipStream_t stream)
{
  const float* x    = (const float*)d_in[0];
  const int*   ei   = (const int*)d_in[1];
  const float* h0   = (const float*)d_in[2];
  const float* c0   = (const float*)d_in[3];
  const float* wih0f = (const float*)d_in[4];
  const float* whh0f = (const float*)d_in[5];
  const float* bih0f = (const float*)d_in[6];
  const float* bhh0f = (const float*)d_in[7];
  const float* wih0b = (const float*)d_in[8];
  const float* whh0b = (const float*)d_in[9];
  const float* bih0b = (const float*)d_in[10];
  const float* bhh0b = (const float*)d_in[11];
  const float* wih1f = (const float*)d_in[12];
  const float* whh1f = (const float*)d_in[13];
  const float* bih1f = (const float*)d_in[14];
  const float* bhh1f = (const float*)d_in[15];
  const float* wih1b = (const float*)d_in[16];
  const float* whh1b = (const float*)d_in[17];
  const float* bih1b = (const float*)d_in[18];
  const float* bhh1b = (const float*)d_in[19];
  const float* W1 = (const float*)d_in[20];
  const float* b1 = (const float*)d_in[21];
  const float* W2 = (const float*)d_in[22];
  const float* b2 = (const float*)d_in[23];

  char* ws = (char*)d_ws;
  int*   deg  = (int*)(ws + OFF_DEG);
  float* dinv = (float*)(ws + OFF_DINV);
  bf16* B0f = (bf16*)(ws + OFF_B0F);
  bf16* B0b = (bf16*)(ws + OFF_B0B);
  bf16* B1f = (bf16*)(ws + OFF_B1F);
  bf16* B1b = (bf16*)(ws + OFF_B1B);
  bf16* BW1 = (bf16*)(ws + OFF_BW1);
  bf16* BW2 = (bf16*)(ws + OFF_BW2);
  bf16* A0f = (bf16*)(ws + OFF_A0F);
  bf16* A0b = (bf16*)(ws + OFF_A0B);
  bf16* A1f = (bf16*)(ws + OFF_A1F);
  bf16* A1b = (bf16*)(ws + OFF_A1B);
  bf16* Afeat = (bf16*)(ws + OFF_AFEAT);
  float* g     = (float*)(ws + OFF_G);
  float* adjf  = (float*)(ws + OFF_ADJF);
  bf16*  adjb  = (bf16*)(ws + OFF_ADJB);
  float* xwt1f = (float*)(ws + OFF_XWT1F);
  bf16*  xwt1b = (bf16*)(ws + OFF_XWT1B);
  float* out1  = (float*)(ws + OFF_OUT1);
  bf16*  h1bf  = (bf16*)(ws + OFF_H1);
  float* xwt2f = (float*)(ws + OFF_XWT2F);
  bf16*  xwt2b = (bf16*)(ws + OFF_XWT2B);
  float* outp = (float*)d_out;

  // degree + norm
  hipMemsetAsync(deg, 0, (size_t)NN*4, stream);
  deg_count<<<dim3((EE+255)/256), 256, 0, stream>>>(ei + EE, deg);
  calc_dinv<<<dim3(15), 256, 0, stream>>>(deg, dinv);

  // weight packing (bf16, zero-padded K)
  pack_B<<<dim3(5, 2048), 256, 0, stream>>>(wih0f, whh0f, B0f, 588, 1120);
  pack_B<<<dim3(5, 2048), 256, 0, stream>>>(wih0b, whh0b, B0b, 588, 1120);
  pack_B<<<dim3(6, 2048), 256, 0, stream>>>(wih1f, whh1f, B1f, 1024, 1536);
  pack_B<<<dim3(6, 2048), 256, 0, stream>>>(wih1b, whh1b, B1b, 1024, 1536);
  pack_BT<<<dim3(6, 512), 256, 0, stream>>>(W1, BW1, 512, 1408);
  pack_BT<<<dim3(2, 256), 256, 0, stream>>>(W2, BW2, 256, 512);

  // activations packing
  pack_A0<<<dim3(5, MP), 256, 0, stream>>>(x, h0, A0f, A0b);
  pack_A1h<<<dim3(2, MP), 256, 0, stream>>>(h0 + (size_t)2*NH, h0 + (size_t)3*NH, A1f, A1b);

  // LSTM layer 0
  gemm_bt<<<dim3(16, 29), 256, 0, stream>>>(A0f, B0f, g, nullptr, 1120, 2048, MP);
  lstm_gate<<<dim3(7200), 256, 0, stream>>>(g, c0 + (size_t)0*NH, bih0f, bhh0f,
                                            A1f, A1b, 1536, 1.0f);
  gemm_bt<<<dim3(16, 29), 256, 0, stream>>>(A0b, B0b, g, nullptr, 1120, 2048, MP);
  lstm_gate<<<dim3(7200), 256, 0, stream>>>(g, c0 + (size_t)1*NH, bih0b, bhh0b,
                                            A1f + 512, A1b + 512, 1536, 1.0f);

  // feat: prot part (A0 dead; Afeat overlays it)
  pack_prot<<<dim3(2, MP), 256, 0, stream>>>(x, Afeat);

  // LSTM layer 1 (writes x_p/100 into feat)
  gemm_bt<<<dim3(16, 29), 256, 0, stream>>>(A1f, B1f, g, nullptr, 1536, 2048, MP);
  lstm_gate<<<dim3(7200), 256, 0, stream>>>(g, c0 + (size_t)2*NH, bih1f, bhh1f,
                                            Afeat + 384, nullptr, 1408, 0.01f);
  gemm_bt<<<dim3(16, 29), 256, 0, stream>>>(A1b, B1b, g, nullptr, 1536, 2048, MP);
  lstm_gate<<<dim3(7200), 256, 0, stream>>>(g, c0 + (size_t)3*NH, bih1b, bhh1b,
                                            Afeat + 896, nullptr, 1408, 0.01f);

  // dense normalized adjacency (A1/g regions dead now)
  hipMemsetAsync(adjf, 0, (size_t)NN*KADJ*4, stream);
  adj_scatter<<<dim3((EE+NN+255)/256), 256, 0, stream>>>(ei, ei + EE, dinv, adjf);

  // XW1^T = W1^T @ feat^T  (fp32, 512 x 3712)
  gemm_bt<<<dim3(29, 4), 256, 0, stream>>>(BW1, Afeat, xwt1f, nullptr, 1408, MP, 512);
  cvt_bf<<<dim3(15, 512), 256, 0, stream>>>(xwt1f, MP, xwt1b, 512, NN);
  cvt_bf<<<dim3(15, MP), 256, 0, stream>>>(adjf, KADJ, adjb, NN, KADJ);

  // out1 = Adj @ XW1 + b1 ; relu ; bf16
  gemm_bt<<<dim3(4, 29), 256, 0, stream>>>(adjb, xwt1b, out1, b1, KADJ, 512, MP);
  relu_bf<<<dim3(MP*512/256), 256, 0, stream>>>(out1, h1bf, MP*512);

  // XW2^T = W2^T @ h1^T  (fp32, 256 x 3712)
  gemm_bt<<<dim3(29, 2), 256, 0, stream>>>(BW2, h1bf, xwt2f, nullptr, 512, MP, 256);
  cvt_bf<<<dim3(15, 256), 256, 0, stream>>>(xwt2f, MP, xwt2b, 256, NN);

  // out = Adj @ XW2 + b2  (rows < 3600 only -> d_out)
  gemm_bt<<<dim3(2, 29), 256, 0, stream>>>(adjb, xwt2b, outp, b2, KADJ, 256, NN);
}

// Round 3
// 448.773 us; speedup vs baseline: 2.0048x; 1.3469x over previous
//
#include <hip/hip_runtime.h>
#include <hip/hip_bf16.h>

#define NN 3600
#define MP 3712          // 29*128 padded rows
#define KADJ 3616        // 113*32 padded node-count for adjacency K
#define NH (3600*512)
#define EE 230400

typedef __hip_bfloat16 bf16;
typedef __bf16 bf16x8 __attribute__((ext_vector_type(8)));
typedef float f32x4 __attribute__((ext_vector_type(4)));

typedef __attribute__((address_space(1))) void as1v;
typedef __attribute__((address_space(3))) void as3v;

__device__ __forceinline__ void glds16(void* lds, const void* g) {
  __builtin_amdgcn_global_load_lds((as1v*)(void*)g, (as3v*)lds, 16, 0, 0);
}

// ---------------- GEMM: C(M x N f32) = A(M x Kp bf16) * B(N x Kp bf16)^T + bias
// 128x128 tile, BK=32, 4 waves, 4x4 16x16x32 frags (m97 structure). Non-split.
__global__ __launch_bounds__(256) void gemm_bt(const bf16* __restrict__ A,
                                               const bf16* __restrict__ B,
                                               float* __restrict__ C,
                                               const float* __restrict__ bias,
                                               int Kp, int ldc, int Mv)
{
  __shared__ alignas(16) char smem[16384];
  const int t = threadIdx.x, w = t >> 6, l = t & 63;
  const int mbase = blockIdx.y << 7, nbase = blockIdx.x << 7;
  const size_t ldb = (size_t)Kp * 2;
  const char* gA = (const char*)A + (size_t)(mbase + w*16 + (l>>2)) * ldb + (size_t)((l&3)*16);
  const char* gB = (const char*)B + (size_t)(nbase + w*16 + (l>>2)) * ldb + (size_t)((l&3)*16);
  char* lA = smem + w*1024;
  char* lB = smem + 8192 + w*1024;
  const int wm = (w>>1)*64, wn = (w&1)*64;
  const int aoff = (wm + (l&15))*64 + (l>>4)*16;
  const int boff = 8192 + (wn + (l&15))*64 + (l>>4)*16;
  f32x4 acc[4][4] = {};
  const int steps = Kp >> 5;
  const size_t chunk = ldb * 64;
  for (int kt = 0; kt < steps; ++kt) {
    const size_t ko = (size_t)kt * 64;
    __syncthreads();
    glds16(lA,        gA + ko);
    glds16(lA + 4096, gA + ko + chunk);
    glds16(lB,        gB + ko);
    glds16(lB + 4096, gB + ko + chunk);
    __syncthreads();
    bf16x8 av[4], bv[4];
#pragma unroll
    for (int mi = 0; mi < 4; ++mi) av[mi] = *(const bf16x8*)(smem + aoff + mi*1024);
#pragma unroll
    for (int ni = 0; ni < 4; ++ni) bv[ni] = *(const bf16x8*)(smem + boff + ni*1024);
#pragma unroll
    for (int mi = 0; mi < 4; ++mi)
#pragma unroll
      for (int ni = 0; ni < 4; ++ni)
        acc[mi][ni] = __builtin_amdgcn_mfma_f32_16x16x32_bf16(av[mi], bv[ni], acc[mi][ni], 0, 0, 0);
  }
  const int crow = mbase + wm + ((l>>4)<<2);
  const int ccol = nbase + wn + (l&15);
#pragma unroll
  for (int mi = 0; mi < 4; ++mi)
#pragma unroll
    for (int ni = 0; ni < 4; ++ni) {
      const float bv2 = bias ? bias[ccol + ni*16] : 0.f;
      float* cp = C + (size_t)(crow + mi*16)*ldc + (ccol + ni*16);
#pragma unroll
      for (int j = 0; j < 4; ++j) {
        const int r = crow + mi*16 + j;
        if (r < Mv) cp[(size_t)j*ldc] = acc[mi][ni][j] + bv2;
      }
    }
}

// ---------------- split-K GEMM: partial z writes Cp + z*(gridDim.y*128*ldc)
__global__ __launch_bounds__(256) void gemm_bt_sk(const bf16* __restrict__ A,
                                                  const bf16* __restrict__ B,
                                                  float* __restrict__ Cp,
                                                  int Kp, int ldc, int ksteps)
{
  __shared__ alignas(16) char smem[16384];
  const int t = threadIdx.x, w = t >> 6, l = t & 63;
  const int mbase = blockIdx.y << 7, nbase = blockIdx.x << 7;
  const int total = Kp >> 5;
  const int kstart = blockIdx.z * ksteps;
  int steps = total - kstart; if (steps > ksteps) steps = ksteps;
  const size_t ldb = (size_t)Kp * 2;
  const char* gA = (const char*)A + (size_t)(mbase + w*16 + (l>>2)) * ldb
                   + (size_t)((l&3)*16) + (size_t)kstart*64;
  const char* gB = (const char*)B + (size_t)(nbase + w*16 + (l>>2)) * ldb
                   + (size_t)((l&3)*16) + (size_t)kstart*64;
  char* lA = smem + w*1024;
  char* lB = smem + 8192 + w*1024;
  const int wm = (w>>1)*64, wn = (w&1)*64;
  const int aoff = (wm + (l&15))*64 + (l>>4)*16;
  const int boff = 8192 + (wn + (l&15))*64 + (l>>4)*16;
  f32x4 acc[4][4] = {};
  const size_t chunk = ldb * 64;
  for (int kt = 0; kt < steps; ++kt) {
    const size_t ko = (size_t)kt * 64;
    __syncthreads();
    glds16(lA,        gA + ko);
    glds16(lA + 4096, gA + ko + chunk);
    glds16(lB,        gB + ko);
    glds16(lB + 4096, gB + ko + chunk);
    __syncthreads();
    bf16x8 av[4], bv[4];
#pragma unroll
    for (int mi = 0; mi < 4; ++mi) av[mi] = *(const bf16x8*)(smem + aoff + mi*1024);
#pragma unroll
    for (int ni = 0; ni < 4; ++ni) bv[ni] = *(const bf16x8*)(smem + boff + ni*1024);
#pragma unroll
    for (int mi = 0; mi < 4; ++mi)
#pragma unroll
      for (int ni = 0; ni < 4; ++ni)
        acc[mi][ni] = __builtin_amdgcn_mfma_f32_16x16x32_bf16(av[mi], bv[ni], acc[mi][ni], 0, 0, 0);
  }
  float* Cz = Cp + (size_t)blockIdx.z * ((size_t)(gridDim.y << 7) * ldc);
  const int crow = mbase + wm + ((l>>4)<<2);
  const int ccol = nbase + wn + (l&15);
#pragma unroll
  for (int mi = 0; mi < 4; ++mi)
#pragma unroll
    for (int ni = 0; ni < 4; ++ni) {
      float* cp = Cz + (size_t)(crow + mi*16)*ldc + (ccol + ni*16);
#pragma unroll
      for (int j = 0; j < 4; ++j) cp[(size_t)j*ldc] = acc[mi][ni][j];
    }
}

// ---------------- reduce kernels ----------------
// xwt reduce: partials Z x (R x MP) fp32 -> dst bf16 (R x KADJ), zero for k>=NN
__global__ void reduce_bf_pad(const float* __restrict__ p, bf16* __restrict__ dst, int Z)
{
  int k = blockIdx.x*256 + threadIdx.x;
  int r = blockIdx.y;
  if (k >= KADJ) return;
  const size_t psz = (size_t)gridDim.y * MP;
  float s = 0.f;
  if (k < NN)
    for (int z = 0; z < Z; ++z) s += p[(size_t)z*psz + (size_t)r*MP + k];
  dst[(size_t)r*KADJ + k] = __float2bfloat16(s);
}

// agg1 reduce: 4 partials (MP x 512) + b1, relu, bf16 -> h1bf
__global__ void reduce_relu_bf(const float* __restrict__ p, const float* __restrict__ b,
                               bf16* __restrict__ dst)
{
  int idx = blockIdx.x*256 + threadIdx.x;   // MP*512
  int f = idx & 511;
  float s = b[f];
#pragma unroll
  for (int z = 0; z < 4; ++z) s += p[(size_t)z*MP*512 + idx];
  dst[idx] = __float2bfloat16(fmaxf(s, 0.f));
}

// agg2 reduce: 8 partials (MP x 256) + b2 -> out (NN x 256 fp32)
__global__ void reduce_bias_out(const float* __restrict__ p, const float* __restrict__ b,
                                float* __restrict__ out)
{
  int idx = blockIdx.x*256 + threadIdx.x;   // NN*256
  if (idx >= NN*256) return;
  int f = idx & 255;
  float s = b[f];
#pragma unroll
  for (int z = 0; z < 8; ++z) s += p[(size_t)z*MP*256 + idx];
  out[idx] = s;
}

// ---------------- packing kernels ----------------
__global__ void pack_B(const float* __restrict__ wih, const float* __restrict__ whh,
                       bf16* __restrict__ dst, int kx, int Kp)
{
  int col = blockIdx.x*256 + threadIdx.x;
  int row = blockIdx.y;
  if (col >= Kp) return;
  float v = 0.f;
  if (col < kx) v = wih[(size_t)row*kx + col];
  else if (col < kx + 512) v = whh[(size_t)row*512 + (col - kx)];
  dst[(size_t)row*Kp + col] = __float2bfloat16(v);
}

__global__ void pack_BT(const float* __restrict__ W, bf16* __restrict__ dst, int Nc, int K)
{
  int k = blockIdx.x*256 + threadIdx.x;
  int n = blockIdx.y;
  if (k >= K) return;
  dst[(size_t)n*K + k] = __float2bfloat16(W[(size_t)k*Nc + n]);
}

__global__ void pack_A0(const float* __restrict__ x, const float* __restrict__ h0,
                        bf16* __restrict__ a0f, bf16* __restrict__ a0b)
{
  int col = blockIdx.x*256 + threadIdx.x;  // [0,1120)
  int n = blockIdx.y;                      // [0,3712)
  if (col >= 1120) return;
  float vf = 0.f, vb = 0.f;
  if (n < NN) {
    if (col < 588) { vf = vb = x[(size_t)n*972 + col]; }
    else if (col < 1100) {
      vf = h0[(size_t)n*512 + (col-588)];
      vb = h0[(size_t)NH + (size_t)n*512 + (col-588)];
    }
  }
  a0f[(size_t)n*1120 + col] = __float2bfloat16(vf);
  a0b[(size_t)n*1120 + col] = __float2bfloat16(vb);
}

__global__ void pack_A1h(const float* __restrict__ h2, const float* __restrict__ h3,
                         bf16* __restrict__ a1f, bf16* __restrict__ a1b)
{
  int j = blockIdx.x*256 + threadIdx.x;    // [0,512)
  int n = blockIdx.y;
  if (j >= 512) return;
  float vf = (n < NN) ? h2[(size_t)n*512 + j] : 0.f;
  float vb = (n < NN) ? h3[(size_t)n*512 + j] : 0.f;
  a1f[(size_t)n*1536 + 1024 + j] = __float2bfloat16(vf);
  a1b[(size_t)n*1536 + 1024 + j] = __float2bfloat16(vb);
}

__global__ void pack_prot(const float* __restrict__ x, bf16* __restrict__ afeat)
{
  int k = blockIdx.x*256 + threadIdx.x;    // [0,384)
  int n = blockIdx.y;
  if (k >= 384) return;
  float v = (n < NN) ? x[(size_t)n*972 + 588 + k] : 0.f;
  afeat[(size_t)n*1408 + k] = __float2bfloat16(v);
}

// ---------------- degree / norm ----------------
__global__ void deg_count(const int* __restrict__ ecols, int* __restrict__ deg)
{
  int e = blockIdx.x*256 + threadIdx.x;
  if (e < EE) atomicAdd(&deg[ecols[e]], 1);
}

__global__ void calc_dinv(const int* __restrict__ deg, float* __restrict__ dinv)
{
  int n = blockIdx.x*256 + threadIdx.x;
  if (n < NN) dinv[n] = 1.0f / sqrtf((float)(deg[n] + 1));
}

// ---------------- dense normalized adjacency build ----------------
__global__ void adj_scatter(const int* __restrict__ er, const int* __restrict__ ec,
                            const float* __restrict__ dinv, float* __restrict__ adjf)
{
  int e = blockIdx.x*256 + threadIdx.x;
  if (e < EE) {
    int r = er[e], c = ec[e];
    atomicAdd(&adjf[(size_t)c*KADJ + r], dinv[r]*dinv[c]);
  } else if (e < EE + NN) {
    int n = e - EE;
    float d = dinv[n];
    atomicAdd(&adjf[(size_t)n*KADJ + n], d*d);
  }
}

__global__ void cvt_bf(const float* __restrict__ src, int lds,
                       bf16* __restrict__ dst, int rv, int kv)
{
  int k = blockIdx.x*256 + threadIdx.x;
  int r = blockIdx.y;
  if (k >= KADJ) return;
  float v = (r < rv && k < kv) ? src[(size_t)r*lds + k] : 0.f;
  dst[(size_t)r*KADJ + k] = __float2bfloat16(v);
}

// ---------------- LSTM gate fuse ----------------
__device__ __forceinline__ float sigm(float v) { return 1.0f / (1.0f + expf(-v)); }

__global__ void lstm_gate(const float* __restrict__ g, const float* __restrict__ c0,
                          const float* __restrict__ bih, const float* __restrict__ bhh,
                          bf16* __restrict__ d1, bf16* __restrict__ d2,
                          int ld, float scale)
{
  int idx = blockIdx.x*256 + threadIdx.x;
  int n = idx >> 9, j = idx & 511;
  size_t gb = (size_t)n * 2048;
  float gi = g[gb + j]        + bih[j]        + bhh[j];
  float gf = g[gb + 512 + j]  + bih[512+j]    + bhh[512+j];
  float gg = g[gb + 1024 + j] + bih[1024+j]   + bhh[1024+j];
  float go = g[gb + 1536 + j] + bih[1536+j]   + bhh[1536+j];
  float c2 = sigm(gf) * c0[(size_t)n*512 + j] + sigm(gi) * tanhf(gg);
  float h = sigm(go) * tanhf(c2) * scale;
  bf16 hb = __float2bfloat16(h);
  d1[(size_t)n*ld + j] = hb;
  if (d2) d2[(size_t)n*ld + j] = hb;
}

// ---------------- workspace layout (bytes), total <= 93,339,648 (proven) ----
#define OFF_DEG   ((size_t)0)
#define OFF_DINV  ((size_t)16384)
#define OFF_BW2   ((size_t)32768)
#define OFF_B0F   ((size_t)294912)
#define OFF_B0B   ((size_t)4882432)
#define OFF_B1F   ((size_t)9469952)
#define OFF_B1B   ((size_t)15761408)
#define OFF_BW1   ((size_t)22052864)
#define OFF_A0F   ((size_t)23494656)
#define OFF_A0B   ((size_t)31809536)
#define OFF_A1F   ((size_t)40124416)
#define OFF_A1B   ((size_t)51527680)
#define OFF_G     ((size_t)62930944)   // 30,408,704 -> 93,339,648
// ---- overlays (temporal reuse; comments give live range) ----
#define OFF_AFEAT OFF_A0F              // alive: pack_prot .. xwt1 gemm
#define OFF_XW1P  OFF_G                // xwt1 partials 30,408,704 (g dead after gates)
#define OFF_XWT1B OFF_B0F              // 3,702,784 (B0f dead after L0)
#define OFF_ADJF  ((size_t)40124416)   // 52,070,400 -> 92,194,816 (A1+g dead; after xwt1)
#define OFF_ADJB  ((size_t)4194304)    // 26,845,184 -> 31,039,488 (B0b/B1/BW1/Afeat dead)
#define OFF_H1P   ((size_t)40124416)   // agg1 partials 30,408,704 -> 70,533,120 (adjf dead)
#define OFF_H1    ((size_t)70533120)   // 3,801,088 -> 74,334,208
#define OFF_XW2P  ((size_t)74334208)   // 15,204,352 -> 89,538,560
#define OFF_XWT2B ((size_t)89538560)   // 1,851,392 -> 91,389,952
#define OFF_O2P   ((size_t)40124416)   // agg2 partials 30,408,704 (h1p dead, below h1bf)

extern "C" void kernel_launch(void* const* d_in, const int* in_sizes, int n_in,
                              void* d_out, int out_size, void* d_ws, size_t ws_size,
                              hipStream_t stream)
{
  const float* x    = (const float*)d_in[0];
  const int*   ei   = (const int*)d_in[1];
  const float* h0   = (const float*)d_in[2];
  const float* c0   = (const float*)d_in[3];
  const float* wih0f = (const float*)d_in[4];
  const float* whh0f = (const float*)d_in[5];
  const float* bih0f = (const float*)d_in[6];
  const float* bhh0f = (const float*)d_in[7];
  const float* wih0b = (const float*)d_in[8];
  const float* whh0b = (const float*)d_in[9];
  const float* bih0b = (const float*)d_in[10];
  const float* bhh0b = (const float*)d_in[11];
  const float* wih1f = (const float*)d_in[12];
  const float* whh1f = (const float*)d_in[13];
  const float* bih1f = (const float*)d_in[14];
  const float* bhh1f = (const float*)d_in[15];
  const float* wih1b = (const float*)d_in[16];
  const float* whh1b = (const float*)d_in[17];
  const float* bih1b = (const float*)d_in[18];
  const float* bhh1b = (const float*)d_in[19];
  const float* W1 = (const float*)d_in[20];
  const float* b1 = (const float*)d_in[21];
  const float* W2 = (const float*)d_in[22];
  const float* b2 = (const float*)d_in[23];

  char* ws = (char*)d_ws;
  int*   deg  = (int*)(ws + OFF_DEG);
  float* dinv = (float*)(ws + OFF_DINV);
  bf16* B0f = (bf16*)(ws + OFF_B0F);
  bf16* B0b = (bf16*)(ws + OFF_B0B);
  bf16* B1f = (bf16*)(ws + OFF_B1F);
  bf16* B1b = (bf16*)(ws + OFF_B1B);
  bf16* BW1 = (bf16*)(ws + OFF_BW1);
  bf16* BW2 = (bf16*)(ws + OFF_BW2);
  bf16* A0f = (bf16*)(ws + OFF_A0F);
  bf16* A0b = (bf16*)(ws + OFF_A0B);
  bf16* A1f = (bf16*)(ws + OFF_A1F);
  bf16* A1b = (bf16*)(ws + OFF_A1B);
  bf16* Afeat = (bf16*)(ws + OFF_AFEAT);
  float* g     = (float*)(ws + OFF_G);
  float* xw1p  = (float*)(ws + OFF_XW1P);
  bf16*  xwt1b = (bf16*)(ws + OFF_XWT1B);
  float* adjf  = (float*)(ws + OFF_ADJF);
  bf16*  adjb  = (bf16*)(ws + OFF_ADJB);
  float* h1p   = (float*)(ws + OFF_H1P);
  bf16*  h1bf  = (bf16*)(ws + OFF_H1);
  float* xw2p  = (float*)(ws + OFF_XW2P);
  bf16*  xwt2b = (bf16*)(ws + OFF_XWT2B);
  float* o2p   = (float*)(ws + OFF_O2P);
  float* outp = (float*)d_out;

  // degree + norm
  hipMemsetAsync(deg, 0, (size_t)NN*4, stream);
  deg_count<<<dim3((EE+255)/256), 256, 0, stream>>>(ei + EE, deg);
  calc_dinv<<<dim3(15), 256, 0, stream>>>(deg, dinv);

  // weight packing
  pack_B<<<dim3(5, 2048), 256, 0, stream>>>(wih0f, whh0f, B0f, 588, 1120);
  pack_B<<<dim3(5, 2048), 256, 0, stream>>>(wih0b, whh0b, B0b, 588, 1120);
  pack_B<<<dim3(6, 2048), 256, 0, stream>>>(wih1f, whh1f, B1f, 1024, 1536);
  pack_B<<<dim3(6, 2048), 256, 0, stream>>>(wih1b, whh1b, B1b, 1024, 1536);
  pack_BT<<<dim3(6, 512), 256, 0, stream>>>(W1, BW1, 512, 1408);
  pack_BT<<<dim3(2, 256), 256, 0, stream>>>(W2, BW2, 256, 512);

  // activations packing
  pack_A0<<<dim3(5, MP), 256, 0, stream>>>(x, h0, A0f, A0b);
  pack_A1h<<<dim3(2, MP), 256, 0, stream>>>(h0 + (size_t)2*NH, h0 + (size_t)3*NH, A1f, A1b);

  // LSTM layer 0
  gemm_bt<<<dim3(16, 29), 256, 0, stream>>>(A0f, B0f, g, nullptr, 1120, 2048, MP);
  lstm_gate<<<dim3(7200), 256, 0, stream>>>(g, c0 + (size_t)0*NH, bih0f, bhh0f,
                                            A1f, A1b, 1536, 1.0f);
  gemm_bt<<<dim3(16, 29), 256, 0, stream>>>(A0b, B0b, g, nullptr, 1120, 2048, MP);
  lstm_gate<<<dim3(7200), 256, 0, stream>>>(g, c0 + (size_t)1*NH, bih0b, bhh0b,
                                            A1f + 512, A1b + 512, 1536, 1.0f);

  // feat: prot part (A0 dead; Afeat overlays it)
  pack_prot<<<dim3(2, MP), 256, 0, stream>>>(x, Afeat);

  // LSTM layer 1
  gemm_bt<<<dim3(16, 29), 256, 0, stream>>>(A1f, B1f, g, nullptr, 1536, 2048, MP);
  lstm_gate<<<dim3(7200), 256, 0, stream>>>(g, c0 + (size_t)2*NH, bih1f, bhh1f,
                                            Afeat + 384, nullptr, 1408, 0.01f);
  gemm_bt<<<dim3(16, 29), 256, 0, stream>>>(A1b, B1b, g, nullptr, 1536, 2048, MP);
  lstm_gate<<<dim3(7200), 256, 0, stream>>>(g, c0 + (size_t)3*NH, bih1b, bhh1b,
                                            Afeat + 896, nullptr, 1408, 0.01f);

  // XW1^T = W1^T @ feat^T  split-K=4 (partials over dead g region)
  gemm_bt_sk<<<dim3(29, 4, 4), 256, 0, stream>>>(BW1, Afeat, xw1p, 1408, MP, 11);
  reduce_bf_pad<<<dim3(15, 512), 256, 0, stream>>>(xw1p, xwt1b, 4);

  // dense normalized adjacency (A1+g dead after xwt1)
  hipMemsetAsync(adjf, 0, (size_t)NN*KADJ*4, stream);
  adj_scatter<<<dim3((EE+NN+255)/256), 256, 0, stream>>>(ei, ei + EE, dinv, adjf);
  cvt_bf<<<dim3(15, MP), 256, 0, stream>>>(adjf, KADJ, adjb, NN, KADJ);

  // out1 = relu(Adj @ XW1 + b1) -> bf16, split-K=4 (113 steps -> 29,29,29,26)
  gemm_bt_sk<<<dim3(4, 29, 4), 256, 0, stream>>>(adjb, xwt1b, h1p, KADJ, 512, 29);
  reduce_relu_bf<<<dim3(MP*512/256), 256, 0, stream>>>(h1p, b1, h1bf);

  // XW2^T = W2^T @ h1^T  split-K=4
  gemm_bt_sk<<<dim3(29, 2, 4), 256, 0, stream>>>(BW2, h1bf, xw2p, 512, MP, 4);
  reduce_bf_pad<<<dim3(15, 256), 256, 0, stream>>>(xw2p, xwt2b, 4);

  // out = Adj @ XW2 + b2, split-K=8 (113 -> 7x15+8)
  gemm_bt_sk<<<dim3(2, 29, 8), 256, 0, stream>>>(adjb, xwt2b, o2p, KADJ, 256, 15);
  reduce_bias_out<<<dim3(3600), 256, 0, stream>>>(o2p, b2, outp);
}

// Round 4
// 422.632 us; speedup vs baseline: 2.1288x; 1.0619x over previous
//
#include <hip/hip_runtime.h>
#include <hip/hip_bf16.h>

#define NN 3600
#define MP 3712          // 29*128 padded rows
#define KADJ 3616        // 113*32 padded node-count for adjacency K
#define NH (3600*512)
#define EE 230400

typedef __hip_bfloat16 bf16;
typedef __bf16 bf16x8 __attribute__((ext_vector_type(8)));
typedef float f32x4 __attribute__((ext_vector_type(4)));

typedef __attribute__((address_space(1))) void as1v;
typedef __attribute__((address_space(3))) void as3v;

__device__ __forceinline__ void glds16(void* lds, const void* g) {
  __builtin_amdgcn_global_load_lds((as1v*)(void*)g, (as3v*)lds, 16, 0, 0);
}

__device__ __forceinline__ float sigm(float v) { return 1.0f / (1.0f + expf(-v)); }

// ---------------- fused LSTM GEMM (f+b merged, gate epilogue) ----------------
// B is gate-interleaved packed: packed row r <-> gate slot (r>>4)&3, hidden
// j = (r>>6)*16 + (r&15). A wave's 64-col span = 4 gates x 16 hidden units.
// Epilogue: h = sig(o)*tanh(sig(f)*c0 + sig(i)*tanh(g)) * scale -> bf16 d1[,d2]
__global__ __launch_bounds__(256) void gemm_lstm(
    const bf16* __restrict__ Af, const bf16* __restrict__ Bf,
    const float* __restrict__ c0f, const float* __restrict__ bihf,
    const float* __restrict__ bhhf, bf16* __restrict__ d1f, bf16* __restrict__ d2f,
    const bf16* __restrict__ Ab, const bf16* __restrict__ Bb,
    const float* __restrict__ c0b, const float* __restrict__ bihb,
    const float* __restrict__ bhhb, bf16* __restrict__ d1b, bf16* __restrict__ d2b,
    int Kp, int ldd, float scale, int hx)
{
  __shared__ alignas(16) char smem[16384];
  const bool back = (int)blockIdx.x >= hx;
  const bf16* A  = back ? Ab : Af;
  const bf16* B  = back ? Bb : Bf;
  const float* c0 = back ? c0b : c0f;
  const float* bih = back ? bihb : bihf;
  const float* bhh = back ? bhhb : bhhf;
  bf16* d1 = back ? d1b : d1f;
  bf16* d2 = back ? d2b : d2f;
  const int t = threadIdx.x, w = t >> 6, l = t & 63;
  const int mbase = blockIdx.y << 7;
  const int nbase = (back ? blockIdx.x - hx : blockIdx.x) << 7;
  const size_t ldb = (size_t)Kp * 2;
  const char* gA = (const char*)A + (size_t)(mbase + w*16 + (l>>2)) * ldb + (size_t)((l&3)*16);
  const char* gB = (const char*)B + (size_t)(nbase + w*16 + (l>>2)) * ldb + (size_t)((l&3)*16);
  char* lA = smem + w*1024;
  char* lB = smem + 8192 + w*1024;
  const int wm = (w>>1)*64, wn = (w&1)*64;
  const int aoff = (wm + (l&15))*64 + (l>>4)*16;
  const int boff = 8192 + (wn + (l&15))*64 + (l>>4)*16;
  f32x4 acc[4][4] = {};
  const int steps = Kp >> 5;
  const size_t chunk = ldb * 64;
  for (int kt = 0; kt < steps; ++kt) {
    const size_t ko = (size_t)kt * 64;
    __syncthreads();
    glds16(lA,        gA + ko);
    glds16(lA + 4096, gA + ko + chunk);
    glds16(lB,        gB + ko);
    glds16(lB + 4096, gB + ko + chunk);
    __syncthreads();
    bf16x8 av[4], bv[4];
#pragma unroll
    for (int mi = 0; mi < 4; ++mi) av[mi] = *(const bf16x8*)(smem + aoff + mi*1024);
#pragma unroll
    for (int ni = 0; ni < 4; ++ni) bv[ni] = *(const bf16x8*)(smem + boff + ni*1024);
#pragma unroll
    for (int mi = 0; mi < 4; ++mi)
#pragma unroll
      for (int ni = 0; ni < 4; ++ni)
        acc[mi][ni] = __builtin_amdgcn_mfma_f32_16x16x32_bf16(av[mi], bv[ni], acc[mi][ni], 0, 0, 0);
  }
  // hidden index for this lane (16 js per 64-col gate group)
  const int jh = ((nbase + wn) >> 2) + (l & 15);
  const float bI = bih[jh]        + bhh[jh];
  const float bF = bih[512 + jh]  + bhh[512 + jh];
  const float bG = bih[1024 + jh] + bhh[1024 + jh];
  const float bO = bih[1536 + jh] + bhh[1536 + jh];
  const int crow = mbase + wm + ((l>>4)<<2);
#pragma unroll
  for (int mi = 0; mi < 4; ++mi)
#pragma unroll
    for (int jr = 0; jr < 4; ++jr) {
      const int n = crow + mi*16 + jr;
      if (n < NN) {
        const float gi = acc[mi][0][jr] + bI;
        const float gf = acc[mi][1][jr] + bF;
        const float gg = acc[mi][2][jr] + bG;
        const float go = acc[mi][3][jr] + bO;
        const float c2 = sigm(gf) * c0[(size_t)n*512 + jh] + sigm(gi) * tanhf(gg);
        const float h  = sigm(go) * tanhf(c2) * scale;
        const bf16 hb = __float2bfloat16(h);
        d1[(size_t)n*ldd + jh] = hb;
        if (d2) d2[(size_t)n*ldd + jh] = hb;
      }
    }
}

// ---------------- split-K GEMM: partial z writes Cp + z*(gridDim.y*128*ldc)
__global__ __launch_bounds__(256) void gemm_bt_sk(const bf16* __restrict__ A,
                                                  const bf16* __restrict__ B,
                                                  float* __restrict__ Cp,
                                                  int Kp, int ldc, int ksteps)
{
  __shared__ alignas(16) char smem[16384];
  const int t = threadIdx.x, w = t >> 6, l = t & 63;
  const int mbase = blockIdx.y << 7, nbase = blockIdx.x << 7;
  const int total = Kp >> 5;
  const int kstart = blockIdx.z * ksteps;
  int steps = total - kstart; if (steps > ksteps) steps = ksteps;
  const size_t ldb = (size_t)Kp * 2;
  const char* gA = (const char*)A + (size_t)(mbase + w*16 + (l>>2)) * ldb
                   + (size_t)((l&3)*16) + (size_t)kstart*64;
  const char* gB = (const char*)B + (size_t)(nbase + w*16 + (l>>2)) * ldb
                   + (size_t)((l&3)*16) + (size_t)kstart*64;
  char* lA = smem + w*1024;
  char* lB = smem + 8192 + w*1024;
  const int wm = (w>>1)*64, wn = (w&1)*64;
  const int aoff = (wm + (l&15))*64 + (l>>4)*16;
  const int boff = 8192 + (wn + (l&15))*64 + (l>>4)*16;
  f32x4 acc[4][4] = {};
  const size_t chunk = ldb * 64;
  for (int kt = 0; kt < steps; ++kt) {
    const size_t ko = (size_t)kt * 64;
    __syncthreads();
    glds16(lA,        gA + ko);
    glds16(lA + 4096, gA + ko + chunk);
    glds16(lB,        gB + ko);
    glds16(lB + 4096, gB + ko + chunk);
    __syncthreads();
    bf16x8 av[4], bv[4];
#pragma unroll
    for (int mi = 0; mi < 4; ++mi) av[mi] = *(const bf16x8*)(smem + aoff + mi*1024);
#pragma unroll
    for (int ni = 0; ni < 4; ++ni) bv[ni] = *(const bf16x8*)(smem + boff + ni*1024);
#pragma unroll
    for (int mi = 0; mi < 4; ++mi)
#pragma unroll
      for (int ni = 0; ni < 4; ++ni)
        acc[mi][ni] = __builtin_amdgcn_mfma_f32_16x16x32_bf16(av[mi], bv[ni], acc[mi][ni], 0, 0, 0);
  }
  float* Cz = Cp + (size_t)blockIdx.z * ((size_t)(gridDim.y << 7) * ldc);
  const int crow = mbase + wm + ((l>>4)<<2);
  const int ccol = nbase + wn + (l&15);
#pragma unroll
  for (int mi = 0; mi < 4; ++mi)
#pragma unroll
    for (int ni = 0; ni < 4; ++ni) {
      float* cp = Cz + (size_t)(crow + mi*16)*ldc + (ccol + ni*16);
#pragma unroll
      for (int j = 0; j < 4; ++j) cp[(size_t)j*ldc] = acc[mi][ni][j];
    }
}

// ---------------- reduce kernels ----------------
__global__ void reduce_bf_pad(const float* __restrict__ p, bf16* __restrict__ dst, int Z)
{
  int k = blockIdx.x*256 + threadIdx.x;
  int r = blockIdx.y;
  if (k >= KADJ) return;
  const size_t psz = (size_t)gridDim.y * MP;
  float s = 0.f;
  if (k < NN)
    for (int z = 0; z < Z; ++z) s += p[(size_t)z*psz + (size_t)r*MP + k];
  dst[(size_t)r*KADJ + k] = __float2bfloat16(s);
}

__global__ void reduce_relu_bf(const float* __restrict__ p, const float* __restrict__ b,
                               bf16* __restrict__ dst)
{
  int idx = blockIdx.x*256 + threadIdx.x;   // MP*512
  int f = idx & 511;
  float s = b[f];
#pragma unroll
  for (int z = 0; z < 4; ++z) s += p[(size_t)z*MP*512 + idx];
  dst[idx] = __float2bfloat16(fmaxf(s, 0.f));
}

__global__ void reduce_bias_out(const float* __restrict__ p, const float* __restrict__ b,
                                float* __restrict__ out)
{
  int idx = blockIdx.x*256 + threadIdx.x;   // NN*256
  if (idx >= NN*256) return;
  int f = idx & 255;
  float s = b[f];
#pragma unroll
  for (int z = 0; z < 8; ++z) s += p[(size_t)z*MP*256 + idx];
  out[idx] = s;
}

// ---------------- packing kernels ----------------
// gate-interleaved B pack: packed row r <- src row ((r>>4)&3)*512 + (r>>6)*16 + (r&15)
__global__ void pack_B_gi(const float* __restrict__ wih, const float* __restrict__ whh,
                          bf16* __restrict__ dst, int kx, int Kp)
{
  int col = blockIdx.x*256 + threadIdx.x;
  int r = blockIdx.y;
  if (col >= Kp) return;
  int src = (((r>>4)&3)<<9) + ((r>>6)<<4) + (r&15);
  float v = 0.f;
  if (col < kx) v = wih[(size_t)src*kx + col];
  else if (col < kx + 512) v = whh[(size_t)src*512 + (col - kx)];
  dst[(size_t)r*Kp + col] = __float2bfloat16(v);
}

__global__ void pack_BT(const float* __restrict__ W, bf16* __restrict__ dst, int Nc, int K)
{
  int k = blockIdx.x*256 + threadIdx.x;
  int n = blockIdx.y;
  if (k >= K) return;
  dst[(size_t)n*K + k] = __float2bfloat16(W[(size_t)k*Nc + n]);
}

__global__ void pack_A0(const float* __restrict__ x, const float* __restrict__ h0,
                        bf16* __restrict__ a0f, bf16* __restrict__ a0b)
{
  int col = blockIdx.x*256 + threadIdx.x;  // [0,1120)
  int n = blockIdx.y;                      // [0,3712)
  if (col >= 1120) return;
  float vf = 0.f, vb = 0.f;
  if (n < NN) {
    if (col < 588) { vf = vb = x[(size_t)n*972 + col]; }
    else if (col < 1100) {
      vf = h0[(size_t)n*512 + (col-588)];
      vb = h0[(size_t)NH + (size_t)n*512 + (col-588)];
    }
  }
  a0f[(size_t)n*1120 + col] = __float2bfloat16(vf);
  a0b[(size_t)n*1120 + col] = __float2bfloat16(vb);
}

__global__ void pack_A1h(const float* __restrict__ h2, const float* __restrict__ h3,
                         bf16* __restrict__ a1f, bf16* __restrict__ a1b)
{
  int j = blockIdx.x*256 + threadIdx.x;    // [0,512)
  int n = blockIdx.y;
  if (j >= 512) return;
  float vf = (n < NN) ? h2[(size_t)n*512 + j] : 0.f;
  float vb = (n < NN) ? h3[(size_t)n*512 + j] : 0.f;
  a1f[(size_t)n*1536 + 1024 + j] = __float2bfloat16(vf);
  a1b[(size_t)n*1536 + 1024 + j] = __float2bfloat16(vb);
}

__global__ void pack_prot(const float* __restrict__ x, bf16* __restrict__ afeat)
{
  int k = blockIdx.x*256 + threadIdx.x;    // [0,384)
  int n = blockIdx.y;
  if (k >= 384) return;
  float v = (n < NN) ? x[(size_t)n*972 + 588 + k] : 0.f;
  afeat[(size_t)n*1408 + k] = __float2bfloat16(v);
}

// ---------------- degree / norm ----------------
__global__ void deg_count(const int* __restrict__ ecols, int* __restrict__ deg)
{
  int e = blockIdx.x*256 + threadIdx.x;
  if (e < EE) atomicAdd(&deg[ecols[e]], 1);
}

__global__ void calc_dinv(const int* __restrict__ deg, float* __restrict__ dinv)
{
  int n = blockIdx.x*256 + threadIdx.x;
  if (n < NN) dinv[n] = 1.0f / sqrtf((float)(deg[n] + 1));
}

// ---------------- dense normalized adjacency build ----------------
__global__ void adj_scatter(const int* __restrict__ er, const int* __restrict__ ec,
                            const float* __restrict__ dinv, float* __restrict__ adjf)
{
  int e = blockIdx.x*256 + threadIdx.x;
  if (e < EE) {
    int r = er[e], c = ec[e];
    atomicAdd(&adjf[(size_t)c*KADJ + r], dinv[r]*dinv[c]);
  } else if (e < EE + NN) {
    int n = e - EE;
    float d = dinv[n];
    atomicAdd(&adjf[(size_t)n*KADJ + n], d*d);
  }
}

__global__ void cvt_bf(const float* __restrict__ src, int lds,
                       bf16* __restrict__ dst, int rv, int kv)
{
  int k = blockIdx.x*256 + threadIdx.x;
  int r = blockIdx.y;
  if (k >= KADJ) return;
  float v = (r < rv && k < kv) ? src[(size_t)r*lds + k] : 0.f;
  dst[(size_t)r*KADJ + k] = __float2bfloat16(v);
}

// ---------------- workspace layout (bytes), total <= 93,339,648 (proven) ----
#define OFF_DEG   ((size_t)0)
#define OFF_DINV  ((size_t)16384)
#define OFF_BW2   ((size_t)32768)
#define OFF_B0F   ((size_t)294912)
#define OFF_B0B   ((size_t)4882432)
#define OFF_B1F   ((size_t)9469952)
#define OFF_B1B   ((size_t)15761408)
#define OFF_BW1   ((size_t)22052864)
#define OFF_A0F   ((size_t)23494656)
#define OFF_A0B   ((size_t)31809536)
#define OFF_A1F   ((size_t)40124416)
#define OFF_A1B   ((size_t)51527680)
#define OFF_G     ((size_t)62930944)   // now only xw1p partials live here
// ---- overlays (temporal reuse) ----
#define OFF_AFEAT OFF_A0F              // alive: pack_prot .. xwt1 gemm
#define OFF_XW1P  OFF_G                // xwt1 partials 30,408,704
#define OFF_XWT1B OFF_B0F              // 3,702,784 (B0f dead after L0)
#define OFF_ADJF  ((size_t)40124416)   // 52,070,400 (A1+xw1p dead after xwt1+reduce)
#define OFF_ADJB  ((size_t)4194304)    // 26,845,184 (B0b/B1/BW1/Afeat dead)
#define OFF_H1P   ((size_t)40124416)   // agg1 partials 30,408,704 (adjf dead)
#define OFF_H1    ((size_t)70533120)   // 3,801,088
#define OFF_XW2P  ((size_t)74334208)   // 15,204,352
#define OFF_XWT2B ((size_t)89538560)   // 1,851,392 -> 91,389,952
#define OFF_O2P   ((size_t)40124416)   // agg2 partials 30,408,704 (h1p dead)

extern "C" void kernel_launch(void* const* d_in, const int* in_sizes, int n_in,
                              void* d_out, int out_size, void* d_ws, size_t ws_size,
                              hipStream_t stream)
{
  const float* x    = (const float*)d_in[0];
  const int*   ei   = (const int*)d_in[1];
  const float* h0   = (const float*)d_in[2];
  const float* c0   = (const float*)d_in[3];
  const float* wih0f = (const float*)d_in[4];
  const float* whh0f = (const float*)d_in[5];
  const float* bih0f = (const float*)d_in[6];
  const float* bhh0f = (const float*)d_in[7];
  const float* wih0b = (const float*)d_in[8];
  const float* whh0b = (const float*)d_in[9];
  const float* bih0b = (const float*)d_in[10];
  const float* bhh0b = (const float*)d_in[11];
  const float* wih1f = (const float*)d_in[12];
  const float* whh1f = (const float*)d_in[13];
  const float* bih1f = (const float*)d_in[14];
  const float* bhh1f = (const float*)d_in[15];
  const float* wih1b = (const float*)d_in[16];
  const float* whh1b = (const float*)d_in[17];
  const float* bih1b = (const float*)d_in[18];
  const float* bhh1b = (const float*)d_in[19];
  const float* W1 = (const float*)d_in[20];
  const float* b1 = (const float*)d_in[21];
  const float* W2 = (const float*)d_in[22];
  const float* b2 = (const float*)d_in[23];

  char* ws = (char*)d_ws;
  int*   deg  = (int*)(ws + OFF_DEG);
  float* dinv = (float*)(ws + OFF_DINV);
  bf16* B0f = (bf16*)(ws + OFF_B0F);
  bf16* B0b = (bf16*)(ws + OFF_B0B);
  bf16* B1f = (bf16*)(ws + OFF_B1F);
  bf16* B1b = (bf16*)(ws + OFF_B1B);
  bf16* BW1 = (bf16*)(ws + OFF_BW1);
  bf16* BW2 = (bf16*)(ws + OFF_BW2);
  bf16* A0f = (bf16*)(ws + OFF_A0F);
  bf16* A0b = (bf16*)(ws + OFF_A0B);
  bf16* A1f = (bf16*)(ws + OFF_A1F);
  bf16* A1b = (bf16*)(ws + OFF_A1B);
  bf16* Afeat = (bf16*)(ws + OFF_AFEAT);
  float* xw1p  = (float*)(ws + OFF_XW1P);
  bf16*  xwt1b = (bf16*)(ws + OFF_XWT1B);
  float* adjf  = (float*)(ws + OFF_ADJF);
  bf16*  adjb  = (bf16*)(ws + OFF_ADJB);
  float* h1p   = (float*)(ws + OFF_H1P);
  bf16*  h1bf  = (bf16*)(ws + OFF_H1);
  float* xw2p  = (float*)(ws + OFF_XW2P);
  bf16*  xwt2b = (bf16*)(ws + OFF_XWT2B);
  float* o2p   = (float*)(ws + OFF_O2P);
  float* outp = (float*)d_out;

  // degree + norm
  hipMemsetAsync(deg, 0, (size_t)NN*4, stream);
  deg_count<<<dim3((EE+255)/256), 256, 0, stream>>>(ei + EE, deg);
  calc_dinv<<<dim3(15), 256, 0, stream>>>(deg, dinv);

  // weight packing (gate-interleaved for LSTM)
  pack_B_gi<<<dim3(5, 2048), 256, 0, stream>>>(wih0f, whh0f, B0f, 588, 1120);
  pack_B_gi<<<dim3(5, 2048), 256, 0, stream>>>(wih0b, whh0b, B0b, 588, 1120);
  pack_B_gi<<<dim3(6, 2048), 256, 0, stream>>>(wih1f, whh1f, B1f, 1024, 1536);
  pack_B_gi<<<dim3(6, 2048), 256, 0, stream>>>(wih1b, whh1b, B1b, 1024, 1536);
  pack_BT<<<dim3(6, 512), 256, 0, stream>>>(W1, BW1, 512, 1408);
  pack_BT<<<dim3(2, 256), 256, 0, stream>>>(W2, BW2, 256, 512);

  // activations packing
  pack_A0<<<dim3(5, MP), 256, 0, stream>>>(x, h0, A0f, A0b);
  pack_A1h<<<dim3(2, MP), 256, 0, stream>>>(h0 + (size_t)2*NH, h0 + (size_t)3*NH, A1f, A1b);

  // LSTM layer 0: merged f+b, gate fused into epilogue
  gemm_lstm<<<dim3(32, 29), 256, 0, stream>>>(
      A0f, B0f, c0,              bih0f, bhh0f, A1f,       A1b,
      A0b, B0b, c0 + (size_t)NH, bih0b, bhh0b, A1f + 512, A1b + 512,
      1120, 1536, 1.0f, 16);

  // feat: prot part (A0 dead; Afeat overlays it)
  pack_prot<<<dim3(2, MP), 256, 0, stream>>>(x, Afeat);

  // LSTM layer 1: merged f+b, writes x_p/100 into feat
  gemm_lstm<<<dim3(32, 29), 256, 0, stream>>>(
      A1f, B1f, c0 + (size_t)2*NH, bih1f, bhh1f, Afeat + 384, nullptr,
      A1b, B1b, c0 + (size_t)3*NH, bih1b, bhh1b, Afeat + 896, nullptr,
      1536, 1408, 0.01f, 16);

  // XW1^T = W1^T @ feat^T  split-K=4
  gemm_bt_sk<<<dim3(29, 4, 4), 256, 0, stream>>>(BW1, Afeat, xw1p, 1408, MP, 11);
  reduce_bf_pad<<<dim3(15, 512), 256, 0, stream>>>(xw1p, xwt1b, 4);

  // dense normalized adjacency (A1+xw1p dead)
  hipMemsetAsync(adjf, 0, (size_t)NN*KADJ*4, stream);
  adj_scatter<<<dim3((EE+NN+255)/256), 256, 0, stream>>>(ei, ei + EE, dinv, adjf);
  cvt_bf<<<dim3(15, MP), 256, 0, stream>>>(adjf, KADJ, adjb, NN, KADJ);

  // out1 = relu(Adj @ XW1 + b1) -> bf16, split-K=4
  gemm_bt_sk<<<dim3(4, 29, 4), 256, 0, stream>>>(adjb, xwt1b, h1p, KADJ, 512, 29);
  reduce_relu_bf<<<dim3(MP*512/256), 256, 0, stream>>>(h1p, b1, h1bf);

  // XW2^T = W2^T @ h1^T  split-K=4
  gemm_bt_sk<<<dim3(29, 2, 4), 256, 0, stream>>>(BW2, h1bf, xw2p, 512, MP, 4);
  reduce_bf_pad<<<dim3(15, 256), 256, 0, stream>>>(xw2p, xwt2b, 4);

  // out = Adj @ XW2 + b2, split-K=8
  gemm_bt_sk<<<dim3(2, 29, 8), 256, 0, stream>>>(adjb, xwt2b, o2p, KADJ, 256, 15);
  reduce_bias_out<<<dim3(3600), 256, 0, stream>>>(o2p, b2, outp);
}

// Round 5
// 354.771 us; speedup vs baseline: 2.5360x; 1.1913x over previous
//
#include <hip/hip_runtime.h>
#include <hip/hip_bf16.h>

#define NN 3600
#define MP 3712          // 29*128 padded rows
#define KADJ 3616        // 113*32 padded node-count for adjacency K
#define NH (3600*512)
#define EE 230400
#define NKT0 9           // L0 K = 1152 = 9*128 (588+512 padded)
#define NKT1 12          // L1 K = 1536 = 12*128

typedef __hip_bfloat16 bf16;
typedef __bf16 bf16x8 __attribute__((ext_vector_type(8)));
typedef float f32x4 __attribute__((ext_vector_type(4)));
typedef int i32x8 __attribute__((ext_vector_type(8)));
typedef unsigned char u8x16 __attribute__((ext_vector_type(16)));

typedef __attribute__((address_space(1))) void as1v;
typedef __attribute__((address_space(3))) void as3v;

__device__ __forceinline__ void glds16(void* lds, const void* g) {
  __builtin_amdgcn_global_load_lds((as1v*)(void*)g, (as3v*)lds, 16, 0, 0);
}

__device__ __forceinline__ float sigm(float v) { return 1.0f / (1.0f + expf(-v)); }

__device__ __forceinline__ unsigned char f2fp8(float f) {
  return (unsigned char)(__builtin_amdgcn_cvt_pk_fp8_f32(f, 0.f, 0, false) & 0xff);
}

// ---------------- MX-fp8 fused LSTM GEMM (f+b merged, gate epilogue) --------
// Operands tiled: [blk128][kt][kb:4][row:128][32B] fp8 e4m3, K-step = 128.
// B gate-interleaved: packed col R <-> gate (R>>4)&3, hidden ((R>>6)<<4)+(R&15).
// MODE 0: write h (fp8) into BOTH dst1/dst2 tiled-A1 buffers at k = kOff+jh.
// MODE 1: write h*0.01 (bf16) into Afeat row-major at col colOff+jh.
template<int MODE>
__global__ __launch_bounds__(256) void gemm_lstm8(
    const unsigned char* __restrict__ Af, const unsigned char* __restrict__ Bf,
    const float* __restrict__ c0f, const float* __restrict__ bihf,
    const float* __restrict__ bhhf,
    const unsigned char* __restrict__ Ab, const unsigned char* __restrict__ Bb,
    const float* __restrict__ c0b, const float* __restrict__ bihb,
    const float* __restrict__ bhhb,
    void* __restrict__ dst1, void* __restrict__ dst2,
    int nkt, int hx)
{
  __shared__ alignas(16) unsigned char smem[32768];   // A 16KB | B 16KB
  const bool back = (int)blockIdx.x >= hx;
  const unsigned char* A = back ? Ab : Af;
  const unsigned char* B = back ? Bb : Bf;
  const float* c0  = back ? c0b : c0f;
  const float* bih = back ? bihb : bihf;
  const float* bhh = back ? bhhb : bhhf;
  const int t = threadIdx.x, w = t >> 6, l = t & 63;
  const int nblk = back ? (int)blockIdx.x - hx : (int)blockIdx.x;
  const unsigned char* gA = A + (((size_t)blockIdx.y * nkt) << 14) + t*16;
  const unsigned char* gB = B + (((size_t)nblk * nkt) << 14) + t*16;
  unsigned char* lA = smem + w*1024;
  unsigned char* lB = smem + 16384 + w*1024;
  const int wm = (w>>1)*64, wn = (w&1)*64;
  const int kb = l >> 4;
  const int aoff = kb*4096 + (wm + (l&15))*32;
  const int boff = 16384 + kb*4096 + (wn + (l&15))*32;
  f32x4 acc[4][4] = {};
  for (int kt = 0; kt < nkt; ++kt) {
    const size_t ko = (size_t)kt << 14;
    __syncthreads();
    glds16(lA,          gA + ko);
    glds16(lA + 4096,   gA + ko + 4096);
    glds16(lA + 8192,   gA + ko + 8192);
    glds16(lA + 12288,  gA + ko + 12288);
    glds16(lB,          gB + ko);
    glds16(lB + 4096,   gB + ko + 4096);
    glds16(lB + 8192,   gB + ko + 8192);
    glds16(lB + 12288,  gB + ko + 12288);
    __syncthreads();
    i32x8 av[4], bv[4];
#pragma unroll
    for (int mi = 0; mi < 4; ++mi) av[mi] = *(const i32x8*)(smem + aoff + mi*512);
#pragma unroll
    for (int ni = 0; ni < 4; ++ni) bv[ni] = *(const i32x8*)(smem + boff + ni*512);
#pragma unroll
    for (int mi = 0; mi < 4; ++mi)
#pragma unroll
      for (int ni = 0; ni < 4; ++ni)
        acc[mi][ni] = __builtin_amdgcn_mfma_scale_f32_16x16x128_f8f6f4(
            av[mi], bv[ni], acc[mi][ni], 0, 0, 0, 127, 0, 127);
  }
  // C/D layout: col = lane&15, row = (lane>>4)*4 + reg  [m89/m121-128]
  const int jh = (((nblk << 7) + wn) >> 2) + (l & 15);
  const float bI = bih[jh]        + bhh[jh];
  const float bF = bih[512 + jh]  + bhh[512 + jh];
  const float bG = bih[1024 + jh] + bhh[1024 + jh];
  const float bO = bih[1536 + jh] + bhh[1536 + jh];
  const int crow = ((int)blockIdx.y << 7) + wm + ((l>>4)<<2);
  const int kk = (back ? 512 : 0) + jh;
  const size_t kpart = ((size_t)(kk >> 7) << 14) + ((size_t)((kk >> 5) & 3) << 12) + (kk & 31);
  const int colOff = back ? 896 : 384;
#pragma unroll
  for (int mi = 0; mi < 4; ++mi)
#pragma unroll
    for (int jr = 0; jr < 4; ++jr) {
      const int n = crow + mi*16 + jr;
      if (n < NN) {
        const float gi = acc[mi][0][jr] + bI;
        const float gf = acc[mi][1][jr] + bF;
        const float gg = acc[mi][2][jr] + bG;
        const float go = acc[mi][3][jr] + bO;
        const float c2 = sigm(gf) * c0[(size_t)n*512 + jh] + sigm(gi) * tanhf(gg);
        const float h  = sigm(go) * tanhf(c2);
        if (MODE == 0) {
          const unsigned char h8 = f2fp8(h);
          const size_t off = (((size_t)(n >> 7) * NKT1) << 14) + kpart + ((size_t)(n & 127) << 5);
          ((unsigned char*)dst1)[off] = h8;
          ((unsigned char*)dst2)[off] = h8;
        } else {
          ((bf16*)dst1)[(size_t)n*1408 + colOff + jh] = __float2bfloat16(h * 0.01f);
        }
      }
    }
}

// ---------------- split-K GEMM (bf16): partial z writes Cp + z*(gridDim.y*128*ldc)
__global__ __launch_bounds__(256) void gemm_bt_sk(const bf16* __restrict__ A,
                                                  const bf16* __restrict__ B,
                                                  float* __restrict__ Cp,
                                                  int Kp, int ldc, int ksteps)
{
  __shared__ alignas(16) char smem[16384];
  const int t = threadIdx.x, w = t >> 6, l = t & 63;
  const int mbase = blockIdx.y << 7, nbase = blockIdx.x << 7;
  const int total = Kp >> 5;
  const int kstart = blockIdx.z * ksteps;
  int steps = total - kstart; if (steps > ksteps) steps = ksteps;
  const size_t ldb = (size_t)Kp * 2;
  const char* gA = (const char*)A + (size_t)(mbase + w*16 + (l>>2)) * ldb
                   + (size_t)((l&3)*16) + (size_t)kstart*64;
  const char* gB = (const char*)B + (size_t)(nbase + w*16 + (l>>2)) * ldb
                   + (size_t)((l&3)*16) + (size_t)kstart*64;
  char* lA = smem + w*1024;
  char* lB = smem + 8192 + w*1024;
  const int wm = (w>>1)*64, wn = (w&1)*64;
  const int aoff = (wm + (l&15))*64 + (l>>4)*16;
  const int boff = 8192 + (wn + (l&15))*64 + (l>>4)*16;
  f32x4 acc[4][4] = {};
  const size_t chunk = ldb * 64;
  for (int kt = 0; kt < steps; ++kt) {
    const size_t ko = (size_t)kt * 64;
    __syncthreads();
    glds16(lA,        gA + ko);
    glds16(lA + 4096, gA + ko + chunk);
    glds16(lB,        gB + ko);
    glds16(lB + 4096, gB + ko + chunk);
    __syncthreads();
    bf16x8 av[4], bv[4];
#pragma unroll
    for (int mi = 0; mi < 4; ++mi) av[mi] = *(const bf16x8*)(smem + aoff + mi*1024);
#pragma unroll
    for (int ni = 0; ni < 4; ++ni) bv[ni] = *(const bf16x8*)(smem + boff + ni*1024);
#pragma unroll
    for (int mi = 0; mi < 4; ++mi)
#pragma unroll
      for (int ni = 0; ni < 4; ++ni)
        acc[mi][ni] = __builtin_amdgcn_mfma_f32_16x16x32_bf16(av[mi], bv[ni], acc[mi][ni], 0, 0, 0);
  }
  float* Cz = Cp + (size_t)blockIdx.z * ((size_t)(gridDim.y << 7) * ldc);
  const int crow = mbase + wm + ((l>>4)<<2);
  const int ccol = nbase + wn + (l&15);
#pragma unroll
  for (int mi = 0; mi < 4; ++mi)
#pragma unroll
    for (int ni = 0; ni < 4; ++ni) {
      float* cp = Cz + (size_t)(crow + mi*16)*ldc + (ccol + ni*16);
#pragma unroll
      for (int j = 0; j < 4; ++j) cp[(size_t)j*ldc] = acc[mi][ni][j];
    }
}

// ---------------- reduce kernels ----------------
__global__ void reduce_bf_pad(const float* __restrict__ p, bf16* __restrict__ dst, int Z)
{
  int k = blockIdx.x*256 + threadIdx.x;
  int r = blockIdx.y;
  if (k >= KADJ) return;
  const size_t psz = (size_t)gridDim.y * MP;
  float s = 0.f;
  if (k < NN)
    for (int z = 0; z < Z; ++z) s += p[(size_t)z*psz + (size_t)r*MP + k];
  dst[(size_t)r*KADJ + k] = __float2bfloat16(s);
}

__global__ void reduce_relu_bf(const float* __restrict__ p, const float* __restrict__ b,
                               bf16* __restrict__ dst)
{
  int idx = blockIdx.x*256 + threadIdx.x;   // MP*512
  int f = idx & 511;
  float s = b[f];
#pragma unroll
  for (int z = 0; z < 4; ++z) s += p[(size_t)z*MP*512 + idx];
  dst[idx] = __float2bfloat16(fmaxf(s, 0.f));
}

__global__ void reduce_bias_out(const float* __restrict__ p, const float* __restrict__ b,
                                float* __restrict__ out)
{
  int idx = blockIdx.x*256 + threadIdx.x;   // NN*256
  if (idx >= NN*256) return;
  int f = idx & 255;
  float s = b[f];
#pragma unroll
  for (int z = 0; z < 8; ++z) s += p[(size_t)z*MP*256 + idx];
  out[idx] = s;
}

// ---------------- fp8 tiled packing ----------------
// dst layout: [blk128][kt][kb:4][r:128][32B]; thread t covers row t>>1, 16 bytes
// B pack, gate-interleaved: tile col R -> src weight row
__global__ void pack_B_8(const float* __restrict__ wih, const float* __restrict__ whh,
                         unsigned char* __restrict__ dst, int kx, int nkt)
{
  const int kt = blockIdx.x >> 2, kbId = blockIdx.x & 3;
  const int t = threadIdx.x;
  const int r = t >> 1, kio = (t & 1) << 4;
  const int R = ((int)blockIdx.y << 7) + r;
  const int src = (((R >> 4) & 3) << 9) + ((R >> 6) << 4) + (R & 15);
  const int kbase = kt*128 + kbId*32 + kio;
  u8x16 v;
#pragma unroll
  for (int i = 0; i < 16; ++i) {
    const int k = kbase + i;
    float f = 0.f;
    if (k < kx) f = wih[(size_t)src*kx + k];
    else if (k < kx + 512) f = whh[(size_t)src*512 + (k - kx)];
    v[i] = f2fp8(f);
  }
  *(u8x16*)(dst + (((size_t)blockIdx.y*nkt + kt) << 14) + (kbId << 12) + (r << 5) + kio) = v;
}

// A0 pack (both dirs): k<588 = x PES cols; 588..1099 = h0[dir]; else 0
__global__ void pack_A0_8(const float* __restrict__ x, const float* __restrict__ h0,
                          unsigned char* __restrict__ a0f, unsigned char* __restrict__ a0b)
{
  const int kt = blockIdx.x >> 2, kbId = blockIdx.x & 3;
  const int t = threadIdx.x;
  const int r = t >> 1, kio = (t & 1) << 4;
  const int n = ((int)blockIdx.y << 7) + r;
  const int kbase = kt*128 + kbId*32 + kio;
  const float* hsrc = h0 + (size_t)blockIdx.z * NH;
  u8x16 v;
#pragma unroll
  for (int i = 0; i < 16; ++i) {
    const int k = kbase + i;
    float f = 0.f;
    if (n < NN) {
      if (k < 588) f = x[(size_t)n*972 + k];
      else if (k < 1100) f = hsrc[(size_t)n*512 + (k - 588)];
    }
    v[i] = f2fp8(f);
  }
  unsigned char* dst = blockIdx.z ? a0b : a0f;
  *(u8x16*)(dst + (((size_t)blockIdx.y*NKT0 + kt) << 14) + (kbId << 12) + (r << 5) + kio) = v;
}

// A1 init: k in [1024,1536) <- h0[2+dir]
__global__ void pack_A1h_8(const float* __restrict__ h0,
                           unsigned char* __restrict__ a1f, unsigned char* __restrict__ a1b)
{
  const int kt = 8 + (blockIdx.x >> 2), kbId = blockIdx.x & 3;
  const int t = threadIdx.x;
  const int r = t >> 1, kio = (t & 1) << 4;
  const int n = ((int)blockIdx.y << 7) + r;
  const int kbase = kt*128 + kbId*32 + kio;
  const float* hsrc = h0 + (size_t)(2 + blockIdx.z) * NH;
  u8x16 v;
#pragma unroll
  for (int i = 0; i < 16; ++i) {
    const int k = kbase + i;
    float f = (n < NN) ? hsrc[(size_t)n*512 + (k - 1024)] : 0.f;
    v[i] = f2fp8(f);
  }
  unsigned char* dst = blockIdx.z ? a1b : a1f;
  *(u8x16*)(dst + (((size_t)blockIdx.y*NKT1 + kt) << 14) + (kbId << 12) + (r << 5) + kio) = v;
}

// ---------------- bf16 packing (GCN path) ----------------
__global__ void pack_BT(const float* __restrict__ W, bf16* __restrict__ dst, int Nc, int K)
{
  int k = blockIdx.x*256 + threadIdx.x;
  int n = blockIdx.y;
  if (k >= K) return;
  dst[(size_t)n*K + k] = __float2bfloat16(W[(size_t)k*Nc + n]);
}

__global__ void pack_prot(const float* __restrict__ x, bf16* __restrict__ afeat)
{
  int k = blockIdx.x*256 + threadIdx.x;    // [0,384)
  int n = blockIdx.y;
  if (k >= 384) return;
  float v = (n < NN) ? x[(size_t)n*972 + 588 + k] : 0.f;
  afeat[(size_t)n*1408 + k] = __float2bfloat16(v);
}

// ---------------- degree / norm ----------------
__global__ void deg_count(const int* __restrict__ ecols, int* __restrict__ deg)
{
  int e = blockIdx.x*256 + threadIdx.x;
  if (e < EE) atomicAdd(&deg[ecols[e]], 1);
}

__global__ void calc_dinv(const int* __restrict__ deg, float* __restrict__ dinv)
{
  int n = blockIdx.x*256 + threadIdx.x;
  if (n < NN) dinv[n] = 1.0f / sqrtf((float)(deg[n] + 1));
}

// ---------------- dense normalized adjacency build ----------------
__global__ void adj_scatter(const int* __restrict__ er, const int* __restrict__ ec,
                            const float* __restrict__ dinv, float* __restrict__ adjf)
{
  int e = blockIdx.x*256 + threadIdx.x;
  if (e < EE) {
    int r = er[e], c = ec[e];
    atomicAdd(&adjf[(size_t)c*KADJ + r], dinv[r]*dinv[c]);
  } else if (e < EE + NN) {
    int n = e - EE;
    float d = dinv[n];
    atomicAdd(&adjf[(size_t)n*KADJ + n], d*d);
  }
}

__global__ void cvt_bf(const float* __restrict__ src, int lds,
                       bf16* __restrict__ dst, int rv, int kv)
{
  int k = blockIdx.x*256 + threadIdx.x;
  int r = blockIdx.y;
  if (k >= KADJ) return;
  float v = (r < rv && k < kv) ? src[(size_t)r*lds + k] : 0.f;
  dst[(size_t)r*KADJ + k] = __float2bfloat16(v);
}

// ---------------- workspace layout (bytes), total <= 93,339,648 (proven) ----
#define OFF_DEG   ((size_t)0)
#define OFF_DINV  ((size_t)16384)
#define OFF_BW2   ((size_t)32768)
#define OFF_B0F   ((size_t)294912)     // fp8: 2,359,296
#define OFF_B0B   ((size_t)4882432)
#define OFF_B1F   ((size_t)9469952)    // fp8: 3,145,728
#define OFF_B1B   ((size_t)15761408)
#define OFF_BW1   ((size_t)22052864)
#define OFF_A0F   ((size_t)23494656)   // fp8: 4,276,224
#define OFF_A0B   ((size_t)31809536)
#define OFF_A1F   ((size_t)40124416)   // fp8: 5,701,632
#define OFF_A1B   ((size_t)51527680)
#define OFF_G     ((size_t)62930944)
// ---- overlays (temporal reuse) ----
#define OFF_AFEAT OFF_A0F              // alive: pack_prot .. xwt1 gemm
#define OFF_XW1P  OFF_G                // xwt1 partials 30,408,704
#define OFF_XWT1B OFF_B0F              // 3,702,784 (B0 dead after L0)
#define OFF_ADJF  ((size_t)40124416)   // 52,070,400 (A1+xw1p dead after xwt1+reduce)
#define OFF_ADJB  ((size_t)4194304)    // 26,845,184 (B0b/B1/BW1/Afeat dead)
#define OFF_H1P   ((size_t)40124416)   // agg1 partials (adjf dead)
#define OFF_H1    ((size_t)70533120)
#define OFF_XW2P  ((size_t)74334208)
#define OFF_XWT2B ((size_t)89538560)
#define OFF_O2P   ((size_t)40124416)   // agg2 partials (h1p dead)

extern "C" void kernel_launch(void* const* d_in, const int* in_sizes, int n_in,
                              void* d_out, int out_size, void* d_ws, size_t ws_size,
                              hipStream_t stream)
{
  const float* x    = (const float*)d_in[0];
  const int*   ei   = (const int*)d_in[1];
  const float* h0   = (const float*)d_in[2];
  const float* c0   = (const float*)d_in[3];
  const float* wih0f = (const float*)d_in[4];
  const float* whh0f = (const float*)d_in[5];
  const float* bih0f = (const float*)d_in[6];
  const float* bhh0f = (const float*)d_in[7];
  const float* wih0b = (const float*)d_in[8];
  const float* whh0b = (const float*)d_in[9];
  const float* bih0b = (const float*)d_in[10];
  const float* bhh0b = (const float*)d_in[11];
  const float* wih1f = (const float*)d_in[12];
  const float* whh1f = (const float*)d_in[13];
  const float* bih1f = (const float*)d_in[14];
  const float* bhh1f = (const float*)d_in[15];
  const float* wih1b = (const float*)d_in[16];
  const float* whh1b = (const float*)d_in[17];
  const float* bih1b = (const float*)d_in[18];
  const float* bhh1b = (const float*)d_in[19];
  const float* W1 = (const float*)d_in[20];
  const float* b1 = (const float*)d_in[21];
  const float* W2 = (const float*)d_in[22];
  const float* b2 = (const float*)d_in[23];

  char* ws = (char*)d_ws;
  int*   deg  = (int*)(ws + OFF_DEG);
  float* dinv = (float*)(ws + OFF_DINV);
  unsigned char* B0f8 = (unsigned char*)(ws + OFF_B0F);
  unsigned char* B0b8 = (unsigned char*)(ws + OFF_B0B);
  unsigned char* B1f8 = (unsigned char*)(ws + OFF_B1F);
  unsigned char* B1b8 = (unsigned char*)(ws + OFF_B1B);
  bf16* BW1 = (bf16*)(ws + OFF_BW1);
  bf16* BW2 = (bf16*)(ws + OFF_BW2);
  unsigned char* A0f8 = (unsigned char*)(ws + OFF_A0F);
  unsigned char* A0b8 = (unsigned char*)(ws + OFF_A0B);
  unsigned char* A1f8 = (unsigned char*)(ws + OFF_A1F);
  unsigned char* A1b8 = (unsigned char*)(ws + OFF_A1B);
  bf16* Afeat = (bf16*)(ws + OFF_AFEAT);
  float* xw1p  = (float*)(ws + OFF_XW1P);
  bf16*  xwt1b = (bf16*)(ws + OFF_XWT1B);
  float* adjf  = (float*)(ws + OFF_ADJF);
  bf16*  adjb  = (bf16*)(ws + OFF_ADJB);
  float* h1p   = (float*)(ws + OFF_H1P);
  bf16*  h1bf  = (bf16*)(ws + OFF_H1);
  float* xw2p  = (float*)(ws + OFF_XW2P);
  bf16*  xwt2b = (bf16*)(ws + OFF_XWT2B);
  float* o2p   = (float*)(ws + OFF_O2P);
  float* outp = (float*)d_out;

  // degree + norm
  hipMemsetAsync(deg, 0, (size_t)NN*4, stream);
  deg_count<<<dim3((EE+255)/256), 256, 0, stream>>>(ei + EE, deg);
  calc_dinv<<<dim3(15), 256, 0, stream>>>(deg, dinv);

  // weight packing: fp8 tiled (LSTM), bf16 (GCN)
  pack_B_8<<<dim3(NKT0*4, 16), 256, 0, stream>>>(wih0f, whh0f, B0f8, 588, NKT0);
  pack_B_8<<<dim3(NKT0*4, 16), 256, 0, stream>>>(wih0b, whh0b, B0b8, 588, NKT0);
  pack_B_8<<<dim3(NKT1*4, 16), 256, 0, stream>>>(wih1f, whh1f, B1f8, 1024, NKT1);
  pack_B_8<<<dim3(NKT1*4, 16), 256, 0, stream>>>(wih1b, whh1b, B1b8, 1024, NKT1);
  pack_BT<<<dim3(6, 512), 256, 0, stream>>>(W1, BW1, 512, 1408);
  pack_BT<<<dim3(2, 256), 256, 0, stream>>>(W2, BW2, 256, 512);

  // activations packing (fp8 tiled)
  pack_A0_8<<<dim3(NKT0*4, 29, 2), 256, 0, stream>>>(x, h0, A0f8, A0b8);
  pack_A1h_8<<<dim3(16, 29, 2), 256, 0, stream>>>(h0, A1f8, A1b8);

  // LSTM layer 0: MX-fp8, merged f+b, gate fused; writes x1 fp8 into A1f/A1b
  gemm_lstm8<0><<<dim3(32, 29), 256, 0, stream>>>(
      A0f8, B0f8, c0,              bih0f, bhh0f,
      A0b8, B0b8, c0 + (size_t)NH, bih0b, bhh0b,
      A1f8, A1b8, NKT0, 16);

  // feat: prot part (A0 dead; Afeat overlays it)
  pack_prot<<<dim3(2, MP), 256, 0, stream>>>(x, Afeat);

  // LSTM layer 1: MX-fp8, writes x_p/100 bf16 into feat
  gemm_lstm8<1><<<dim3(32, 29), 256, 0, stream>>>(
      A1f8, B1f8, c0 + (size_t)2*NH, bih1f, bhh1f,
      A1b8, B1b8, c0 + (size_t)3*NH, bih1b, bhh1b,
      Afeat, nullptr, NKT1, 16);

  // XW1^T = W1^T @ feat^T  split-K=4 (bf16)
  gemm_bt_sk<<<dim3(29, 4, 4), 256, 0, stream>>>(BW1, Afeat, xw1p, 1408, MP, 11);
  reduce_bf_pad<<<dim3(15, 512), 256, 0, stream>>>(xw1p, xwt1b, 4);

  // dense normalized adjacency (A1+xw1p dead)
  hipMemsetAsync(adjf, 0, (size_t)NN*KADJ*4, stream);
  adj_scatter<<<dim3((EE+NN+255)/256), 256, 0, stream>>>(ei, ei + EE, dinv, adjf);
  cvt_bf<<<dim3(15, MP), 256, 0, stream>>>(adjf, KADJ, adjb, NN, KADJ);

  // out1 = relu(Adj @ XW1 + b1) -> bf16, split-K=4
  gemm_bt_sk<<<dim3(4, 29, 4), 256, 0, stream>>>(adjb, xwt1b, h1p, KADJ, 512, 29);
  reduce_relu_bf<<<dim3(MP*512/256), 256, 0, stream>>>(h1p, b1, h1bf);

  // XW2^T = W2^T @ h1^T  split-K=4
  gemm_bt_sk<<<dim3(29, 2, 4), 256, 0, stream>>>(BW2, h1bf, xw2p, 512, MP, 4);
  reduce_bf_pad<<<dim3(15, 256), 256, 0, stream>>>(xw2p, xwt2b, 4);

  // out = Adj @ XW2 + b2, split-K=8
  gemm_bt_sk<<<dim3(2, 29, 8), 256, 0, stream>>>(adjb, xwt2b, o2p, KADJ, 256, 15);
  reduce_bias_out<<<dim3(3600), 256, 0, stream>>>(o2p, b2, outp);
}

// Round 6
// 341.423 us; speedup vs baseline: 2.6351x; 1.0391x over previous
//
#include <hip/hip_runtime.h>
#include <hip/hip_bf16.h>

#define NN 3600
#define MP 3712          // 29*128 padded rows
#define KADJ 3616        // 113*32 padded node-count for adjacency K
#define NH (3600*512)
#define EE 230400
#define NKT0 9           // L0 K = 1152 = 9*128 (588+512 padded)
#define NKT1 12          // L1 K = 1536 = 12*128

typedef __hip_bfloat16 bf16;
typedef __bf16 bf16x8 __attribute__((ext_vector_type(8)));
typedef float f32x4 __attribute__((ext_vector_type(4)));
typedef int i32x8 __attribute__((ext_vector_type(8)));
typedef unsigned char u8x16 __attribute__((ext_vector_type(16)));

typedef __attribute__((address_space(1))) void as1v;
typedef __attribute__((address_space(3))) void as3v;

__device__ __forceinline__ void glds16(void* lds, const void* g) {
  __builtin_amdgcn_global_load_lds((as1v*)(void*)g, (as3v*)lds, 16, 0, 0);
}

__device__ __forceinline__ float sigm(float v) { return 1.0f / (1.0f + expf(-v)); }

__device__ __forceinline__ unsigned char f2fp8(float f) {
  return (unsigned char)(__builtin_amdgcn_cvt_pk_fp8_f32(f, 0.f, 0, false) & 0xff);
}

// ---------------- MX-fp8 fused LSTM GEMM, 2-phase pipelined ----------------
// Operands tiled: [blk128][kt][kb:4][row:128][32B] fp8 e4m3, K-step = 128.
// B gate-interleaved: packed col R <-> gate (R>>4)&3, hidden ((R>>6)<<4)+(R&15).
// MODE 0: write h (fp8) into BOTH dst1/dst2 tiled-A1 buffers at k = kOff+jh.
// MODE 1: write h*0.01 (bf16) into Afeat row-major at col colOff+jh.
template<int MODE>
__global__ __launch_bounds__(256) void gemm_lstm8(
    const unsigned char* __restrict__ Af, const unsigned char* __restrict__ Bf,
    const float* __restrict__ c0f, const float* __restrict__ bihf,
    const float* __restrict__ bhhf,
    const unsigned char* __restrict__ Ab, const unsigned char* __restrict__ Bb,
    const float* __restrict__ c0b, const float* __restrict__ bihb,
    const float* __restrict__ bhhb,
    void* __restrict__ dst1, void* __restrict__ dst2,
    int nkt, int hx)
{
  __shared__ alignas(16) unsigned char smem[65536];   // 2 x (A 16KB | B 16KB)
  const bool back = (int)blockIdx.x >= hx;
  const unsigned char* A = back ? Ab : Af;
  const unsigned char* B = back ? Bb : Bf;
  const float* c0  = back ? c0b : c0f;
  const float* bih = back ? bihb : bihf;
  const float* bhh = back ? bhhb : bhhf;
  const int t = threadIdx.x, w = t >> 6, l = t & 63;
  const int nblk = back ? (int)blockIdx.x - hx : (int)blockIdx.x;
  const unsigned char* gA = A + (((size_t)blockIdx.y * nkt) << 14) + t*16;
  const unsigned char* gB = B + (((size_t)nblk * nkt) << 14) + t*16;
  const int wm = (w>>1)*64, wn = (w&1)*64;
  const int kb = l >> 4;
  const int aoff = kb*4096 + (wm + (l&15))*32;
  const int boff = 16384 + kb*4096 + (wn + (l&15))*32;
  f32x4 acc[4][4] = {};

  auto STAGE = [&](int buf, int kt) {
    unsigned char* lA = smem + buf*32768 + w*1024;
    unsigned char* lB = smem + buf*32768 + 16384 + w*1024;
    const size_t ko = (size_t)kt << 14;
    glds16(lA,          gA + ko);
    glds16(lA + 4096,   gA + ko + 4096);
    glds16(lA + 8192,   gA + ko + 8192);
    glds16(lA + 12288,  gA + ko + 12288);
    glds16(lB,          gB + ko);
    glds16(lB + 4096,   gB + ko + 4096);
    glds16(lB + 8192,   gB + ko + 8192);
    glds16(lB + 12288,  gB + ko + 12288);
  };

  STAGE(0, 0);
  __syncthreads();                      // drain: buf0 ready
  int cur = 0;
  for (int kt = 0; kt < nkt; ++kt) {
    if (kt + 1 < nkt) STAGE(cur ^ 1, kt + 1);   // issue next-tile loads FIRST
    const unsigned char* base = smem + cur*32768;
    i32x8 av[4], bv[4];
#pragma unroll
    for (int mi = 0; mi < 4; ++mi) av[mi] = *(const i32x8*)(base + aoff + mi*512);
#pragma unroll
    for (int ni = 0; ni < 4; ++ni) bv[ni] = *(const i32x8*)(base + boff + ni*512);
#pragma unroll
    for (int mi = 0; mi < 4; ++mi)
#pragma unroll
      for (int ni = 0; ni < 4; ++ni)
        acc[mi][ni] = __builtin_amdgcn_mfma_scale_f32_16x16x128_f8f6f4(
            av[mi], bv[ni], acc[mi][ni], 0, 0, 0, 127, 0, 127);
    __syncthreads();                    // one drain+barrier per K-tile
    cur ^= 1;
  }
  // C/D layout: col = lane&15, row = (lane>>4)*4 + reg  [m89/m121-128]
  const int jh = (((nblk << 7) + wn) >> 2) + (l & 15);
  const float bI = bih[jh]        + bhh[jh];
  const float bF = bih[512 + jh]  + bhh[512 + jh];
  const float bG = bih[1024 + jh] + bhh[1024 + jh];
  const float bO = bih[1536 + jh] + bhh[1536 + jh];
  const int crow = ((int)blockIdx.y << 7) + wm + ((l>>4)<<2);
  const int kk = (back ? 512 : 0) + jh;
  const size_t kpart = ((size_t)(kk >> 7) << 14) + ((size_t)((kk >> 5) & 3) << 12) + (kk & 31);
  const int colOff = back ? 896 : 384;
#pragma unroll
  for (int mi = 0; mi < 4; ++mi)
#pragma unroll
    for (int jr = 0; jr < 4; ++jr) {
      const int n = crow + mi*16 + jr;
      if (n < NN) {
        const float gi = acc[mi][0][jr] + bI;
        const float gf = acc[mi][1][jr] + bF;
        const float gg = acc[mi][2][jr] + bG;
        const float go = acc[mi][3][jr] + bO;
        const float c2 = sigm(gf) * c0[(size_t)n*512 + jh] + sigm(gi) * tanhf(gg);
        const float h  = sigm(go) * tanhf(c2);
        if (MODE == 0) {
          const unsigned char h8 = f2fp8(h);
          const size_t off = (((size_t)(n >> 7) * NKT1) << 14) + kpart + ((size_t)(n & 127) << 5);
          ((unsigned char*)dst1)[off] = h8;
          ((unsigned char*)dst2)[off] = h8;
        } else {
          ((bf16*)dst1)[(size_t)n*1408 + colOff + jh] = __float2bfloat16(h * 0.01f);
        }
      }
    }
}

// ---------------- split-K GEMM (bf16), 2-phase pipelined --------------------
__global__ __launch_bounds__(256) void gemm_bt_sk(const bf16* __restrict__ A,
                                                  const bf16* __restrict__ B,
                                                  float* __restrict__ Cp,
                                                  int Kp, int ldc, int ksteps)
{
  __shared__ alignas(16) char smem[32768];   // 2 x (A 8KB | B 8KB)
  const int t = threadIdx.x, w = t >> 6, l = t & 63;
  const int mbase = blockIdx.y << 7, nbase = blockIdx.x << 7;
  const int total = Kp >> 5;
  const int kstart = blockIdx.z * ksteps;
  int steps = total - kstart; if (steps > ksteps) steps = ksteps;
  const size_t ldb = (size_t)Kp * 2;
  const char* gA = (const char*)A + (size_t)(mbase + w*16 + (l>>2)) * ldb
                   + (size_t)((l&3)*16) + (size_t)kstart*64;
  const char* gB = (const char*)B + (size_t)(nbase + w*16 + (l>>2)) * ldb
                   + (size_t)((l&3)*16) + (size_t)kstart*64;
  const int wm = (w>>1)*64, wn = (w&1)*64;
  const int aoff = (wm + (l&15))*64 + (l>>4)*16;
  const int boff = 8192 + (wn + (l&15))*64 + (l>>4)*16;
  f32x4 acc[4][4] = {};
  const size_t chunk = ldb * 64;

  auto STAGE = [&](int buf, int kt) {
    char* lA = smem + buf*16384 + w*1024;
    char* lB = smem + buf*16384 + 8192 + w*1024;
    const size_t ko = (size_t)kt * 64;
    glds16(lA,        gA + ko);
    glds16(lA + 4096, gA + ko + chunk);
    glds16(lB,        gB + ko);
    glds16(lB + 4096, gB + ko + chunk);
  };

  STAGE(0, 0);
  __syncthreads();
  int cur = 0;
  for (int kt = 0; kt < steps; ++kt) {
    if (kt + 1 < steps) STAGE(cur ^ 1, kt + 1);
    const char* base = smem + cur*16384;
    bf16x8 av[4], bv[4];
#pragma unroll
    for (int mi = 0; mi < 4; ++mi) av[mi] = *(const bf16x8*)(base + aoff + mi*1024);
#pragma unroll
    for (int ni = 0; ni < 4; ++ni) bv[ni] = *(const bf16x8*)(base + boff + ni*1024);
#pragma unroll
    for (int mi = 0; mi < 4; ++mi)
#pragma unroll
      for (int ni = 0; ni < 4; ++ni)
        acc[mi][ni] = __builtin_amdgcn_mfma_f32_16x16x32_bf16(av[mi], bv[ni], acc[mi][ni], 0, 0, 0);
    __syncthreads();
    cur ^= 1;
  }
  float* Cz = Cp + (size_t)blockIdx.z * ((size_t)(gridDim.y << 7) * ldc);
  const int crow = mbase + wm + ((l>>4)<<2);
  const int ccol = nbase + wn + (l&15);
#pragma unroll
  for (int mi = 0; mi < 4; ++mi)
#pragma unroll
    for (int ni = 0; ni < 4; ++ni) {
      float* cp = Cz + (size_t)(crow + mi*16)*ldc + (ccol + ni*16);
#pragma unroll
      for (int j = 0; j < 4; ++j) cp[(size_t)j*ldc] = acc[mi][ni][j];
    }
}

// ---------------- reduce kernels ----------------
__global__ void reduce_bf_pad(const float* __restrict__ p, bf16* __restrict__ dst, int Z)
{
  int k = blockIdx.x*256 + threadIdx.x;
  int r = blockIdx.y;
  if (k >= KADJ) return;
  const size_t psz = (size_t)gridDim.y * MP;
  float s = 0.f;
  if (k < NN)
    for (int z = 0; z < Z; ++z) s += p[(size_t)z*psz + (size_t)r*MP + k];
  dst[(size_t)r*KADJ + k] = __float2bfloat16(s);
}

__global__ void reduce_relu_bf(const float* __restrict__ p, const float* __restrict__ b,
                               bf16* __restrict__ dst)
{
  int idx = blockIdx.x*256 + threadIdx.x;   // MP*512
  int f = idx & 511;
  float s = b[f];
#pragma unroll
  for (int z = 0; z < 4; ++z) s += p[(size_t)z*MP*512 + idx];
  dst[idx] = __float2bfloat16(fmaxf(s, 0.f));
}

__global__ void reduce_bias_out(const float* __restrict__ p, const float* __restrict__ b,
                                float* __restrict__ out)
{
  int idx = blockIdx.x*256 + threadIdx.x;   // NN*256
  if (idx >= NN*256) return;
  int f = idx & 255;
  float s = b[f];
#pragma unroll
  for (int z = 0; z < 8; ++z) s += p[(size_t)z*MP*256 + idx];
  out[idx] = s;
}

// ---------------- fp8 tiled packing ----------------
// dst layout: [blk128][kt][kb:4][r:128][32B]; thread t covers row t>>1, 16 bytes
__global__ void pack_B_8(const float* __restrict__ wih, const float* __restrict__ whh,
                         unsigned char* __restrict__ dst, int kx, int nkt)
{
  const int kt = blockIdx.x >> 2, kbId = blockIdx.x & 3;
  const int t = threadIdx.x;
  const int r = t >> 1, kio = (t & 1) << 4;
  const int R = ((int)blockIdx.y << 7) + r;
  const int src = (((R >> 4) & 3) << 9) + ((R >> 6) << 4) + (R & 15);
  const int kbase = kt*128 + kbId*32 + kio;
  u8x16 v;
#pragma unroll
  for (int i = 0; i < 16; ++i) {
    const int k = kbase + i;
    float f = 0.f;
    if (k < kx) f = wih[(size_t)src*kx + k];
    else if (k < kx + 512) f = whh[(size_t)src*512 + (k - kx)];
    v[i] = f2fp8(f);
  }
  *(u8x16*)(dst + (((size_t)blockIdx.y*nkt + kt) << 14) + (kbId << 12) + (r << 5) + kio) = v;
}

__global__ void pack_A0_8(const float* __restrict__ x, const float* __restrict__ h0,
                          unsigned char* __restrict__ a0f, unsigned char* __restrict__ a0b)
{
  const int kt = blockIdx.x >> 2, kbId = blockIdx.x & 3;
  const int t = threadIdx.x;
  const int r = t >> 1, kio = (t & 1) << 4;
  const int n = ((int)blockIdx.y << 7) + r;
  const int kbase = kt*128 + kbId*32 + kio;
  const float* hsrc = h0 + (size_t)blockIdx.z * NH;
  u8x16 v;
#pragma unroll
  for (int i = 0; i < 16; ++i) {
    const int k = kbase + i;
    float f = 0.f;
    if (n < NN) {
      if (k < 588) f = x[(size_t)n*972 + k];
      else if (k < 1100) f = hsrc[(size_t)n*512 + (k - 588)];
    }
    v[i] = f2fp8(f);
  }
  unsigned char* dst = blockIdx.z ? a0b : a0f;
  *(u8x16*)(dst + (((size_t)blockIdx.y*NKT0 + kt) << 14) + (kbId << 12) + (r << 5) + kio) = v;
}

__global__ void pack_A1h_8(const float* __restrict__ h0,
                           unsigned char* __restrict__ a1f, unsigned char* __restrict__ a1b)
{
  const int kt = 8 + (blockIdx.x >> 2), kbId = blockIdx.x & 3;
  const int t = threadIdx.x;
  const int r = t >> 1, kio = (t & 1) << 4;
  const int n = ((int)blockIdx.y << 7) + r;
  const int kbase = kt*128 + kbId*32 + kio;
  const float* hsrc = h0 + (size_t)(2 + blockIdx.z) * NH;
  u8x16 v;
#pragma unroll
  for (int i = 0; i < 16; ++i) {
    const int k = kbase + i;
    float f = (n < NN) ? hsrc[(size_t)n*512 + (k - 1024)] : 0.f;
    v[i] = f2fp8(f);
  }
  unsigned char* dst = blockIdx.z ? a1b : a1f;
  *(u8x16*)(dst + (((size_t)blockIdx.y*NKT1 + kt) << 14) + (kbId << 12) + (r << 5) + kio) = v;
}

// ---------------- bf16 packing (GCN path) ----------------
__global__ void pack_BT(const float* __restrict__ W, bf16* __restrict__ dst, int Nc, int K)
{
  int k = blockIdx.x*256 + threadIdx.x;
  int n = blockIdx.y;
  if (k >= K) return;
  dst[(size_t)n*K + k] = __float2bfloat16(W[(size_t)k*Nc + n]);
}

__global__ void pack_prot(const float* __restrict__ x, bf16* __restrict__ afeat)
{
  int k = blockIdx.x*256 + threadIdx.x;    // [0,384)
  int n = blockIdx.y;
  if (k >= 384) return;
  float v = (n < NN) ? x[(size_t)n*972 + 588 + k] : 0.f;
  afeat[(size_t)n*1408 + k] = __float2bfloat16(v);
}

// ---------------- degree / norm ----------------
__global__ void deg_count(const int* __restrict__ ecols, int* __restrict__ deg)
{
  int e = blockIdx.x*256 + threadIdx.x;
  if (e < EE) atomicAdd(&deg[ecols[e]], 1);
}

__global__ void calc_dinv(const int* __restrict__ deg, float* __restrict__ dinv)
{
  int n = blockIdx.x*256 + threadIdx.x;
  if (n < NN) dinv[n] = 1.0f / sqrtf((float)(deg[n] + 1));
}

// ---------------- dense normalized adjacency build ----------------
__global__ void adj_scatter(const int* __restrict__ er, const int* __restrict__ ec,
                            const float* __restrict__ dinv, float* __restrict__ adjf)
{
  int e = blockIdx.x*256 + threadIdx.x;
  if (e < EE) {
    int r = er[e], c = ec[e];
    atomicAdd(&adjf[(size_t)c*KADJ + r], dinv[r]*dinv[c]);
  } else if (e < EE + NN) {
    int n = e - EE;
    float d = dinv[n];
    atomicAdd(&adjf[(size_t)n*KADJ + n], d*d);
  }
}

__global__ void cvt_bf(const float* __restrict__ src, int lds,
                       bf16* __restrict__ dst, int rv, int kv)
{
  int k = blockIdx.x*256 + threadIdx.x;
  int r = blockIdx.y;
  if (k >= KADJ) return;
  float v = (r < rv && k < kv) ? src[(size_t)r*lds + k] : 0.f;
  dst[(size_t)r*KADJ + k] = __float2bfloat16(v);
}

// ---------------- workspace layout (bytes), total <= 93,339,648 (proven) ----
#define OFF_DEG   ((size_t)0)
#define OFF_DINV  ((size_t)16384)
#define OFF_BW2   ((size_t)32768)
#define OFF_B0F   ((size_t)294912)     // fp8: 2,359,296
#define OFF_B0B   ((size_t)4882432)
#define OFF_B1F   ((size_t)9469952)    // fp8: 3,145,728
#define OFF_B1B   ((size_t)15761408)
#define OFF_BW1   ((size_t)22052864)
#define OFF_A0F   ((size_t)23494656)   // fp8: 4,276,224
#define OFF_A0B   ((size_t)31809536)
#define OFF_A1F   ((size_t)40124416)   // fp8: 5,701,632
#define OFF_A1B   ((size_t)51527680)
#define OFF_G     ((size_t)62930944)
// ---- overlays (temporal reuse) ----
#define OFF_AFEAT OFF_A0F              // alive: pack_prot .. xwt1 gemm
#define OFF_XW1P  OFF_G                // xwt1 partials 30,408,704
#define OFF_XWT1B OFF_B0F              // 3,702,784 (B0 dead after L0)
#define OFF_ADJF  ((size_t)40124416)   // 52,070,400 (A1+xw1p dead after xwt1+reduce)
#define OFF_ADJB  ((size_t)4194304)    // 26,845,184 (B0b/B1/BW1/Afeat dead)
#define OFF_H1P   ((size_t)40124416)   // agg1 partials (adjf dead)
#define OFF_H1    ((size_t)70533120)
#define OFF_XW2P  ((size_t)74334208)
#define OFF_XWT2B ((size_t)89538560)
#define OFF_O2P   ((size_t)40124416)   // agg2 partials (h1p dead)

extern "C" void kernel_launch(void* const* d_in, const int* in_sizes, int n_in,
                              void* d_out, int out_size, void* d_ws, size_t ws_size,
                              hipStream_t stream)
{
  const float* x    = (const float*)d_in[0];
  const int*   ei   = (const int*)d_in[1];
  const float* h0   = (const float*)d_in[2];
  const float* c0   = (const float*)d_in[3];
  const float* wih0f = (const float*)d_in[4];
  const float* whh0f = (const float*)d_in[5];
  const float* bih0f = (const float*)d_in[6];
  const float* bhh0f = (const float*)d_in[7];
  const float* wih0b = (const float*)d_in[8];
  const float* whh0b = (const float*)d_in[9];
  const float* bih0b = (const float*)d_in[10];
  const float* bhh0b = (const float*)d_in[11];
  const float* wih1f = (const float*)d_in[12];
  const float* whh1f = (const float*)d_in[13];
  const float* bih1f = (const float*)d_in[14];
  const float* bhh1f = (const float*)d_in[15];
  const float* wih1b = (const float*)d_in[16];
  const float* whh1b = (const float*)d_in[17];
  const float* bih1b = (const float*)d_in[18];
  const float* bhh1b = (const float*)d_in[19];
  const float* W1 = (const float*)d_in[20];
  const float* b1 = (const float*)d_in[21];
  const float* W2 = (const float*)d_in[22];
  const float* b2 = (const float*)d_in[23];

  char* ws = (char*)d_ws;
  int*   deg  = (int*)(ws + OFF_DEG);
  float* dinv = (float*)(ws + OFF_DINV);
  unsigned char* B0f8 = (unsigned char*)(ws + OFF_B0F);
  unsigned char* B0b8 = (unsigned char*)(ws + OFF_B0B);
  unsigned char* B1f8 = (unsigned char*)(ws + OFF_B1F);
  unsigned char* B1b8 = (unsigned char*)(ws + OFF_B1B);
  bf16* BW1 = (bf16*)(ws + OFF_BW1);
  bf16* BW2 = (bf16*)(ws + OFF_BW2);
  unsigned char* A0f8 = (unsigned char*)(ws + OFF_A0F);
  unsigned char* A0b8 = (unsigned char*)(ws + OFF_A0B);
  unsigned char* A1f8 = (unsigned char*)(ws + OFF_A1F);
  unsigned char* A1b8 = (unsigned char*)(ws + OFF_A1B);
  bf16* Afeat = (bf16*)(ws + OFF_AFEAT);
  float* xw1p  = (float*)(ws + OFF_XW1P);
  bf16*  xwt1b = (bf16*)(ws + OFF_XWT1B);
  float* adjf  = (float*)(ws + OFF_ADJF);
  bf16*  adjb  = (bf16*)(ws + OFF_ADJB);
  float* h1p   = (float*)(ws + OFF_H1P);
  bf16*  h1bf  = (bf16*)(ws + OFF_H1);
  float* xw2p  = (float*)(ws + OFF_XW2P);
  bf16*  xwt2b = (bf16*)(ws + OFF_XWT2B);
  float* o2p   = (float*)(ws + OFF_O2P);
  float* outp = (float*)d_out;

  // degree + norm
  hipMemsetAsync(deg, 0, (size_t)NN*4, stream);
  deg_count<<<dim3((EE+255)/256), 256, 0, stream>>>(ei + EE, deg);
  calc_dinv<<<dim3(15), 256, 0, stream>>>(deg, dinv);

  // weight packing: fp8 tiled (LSTM), bf16 (GCN)
  pack_B_8<<<dim3(NKT0*4, 16), 256, 0, stream>>>(wih0f, whh0f, B0f8, 588, NKT0);
  pack_B_8<<<dim3(NKT0*4, 16), 256, 0, stream>>>(wih0b, whh0b, B0b8, 588, NKT0);
  pack_B_8<<<dim3(NKT1*4, 16), 256, 0, stream>>>(wih1f, whh1f, B1f8, 1024, NKT1);
  pack_B_8<<<dim3(NKT1*4, 16), 256, 0, stream>>>(wih1b, whh1b, B1b8, 1024, NKT1);
  pack_BT<<<dim3(6, 512), 256, 0, stream>>>(W1, BW1, 512, 1408);
  pack_BT<<<dim3(2, 256), 256, 0, stream>>>(W2, BW2, 256, 512);

  // activations packing (fp8 tiled)
  pack_A0_8<<<dim3(NKT0*4, 29, 2), 256, 0, stream>>>(x, h0, A0f8, A0b8);
  pack_A1h_8<<<dim3(16, 29, 2), 256, 0, stream>>>(h0, A1f8, A1b8);

  // LSTM layer 0: MX-fp8, merged f+b, gate fused; writes x1 fp8 into A1f/A1b
  gemm_lstm8<0><<<dim3(32, 29), 256, 0, stream>>>(
      A0f8, B0f8, c0,              bih0f, bhh0f,
      A0b8, B0b8, c0 + (size_t)NH, bih0b, bhh0b,
      A1f8, A1b8, NKT0, 16);

  // feat: prot part (A0 dead; Afeat overlays it)
  pack_prot<<<dim3(2, MP), 256, 0, stream>>>(x, Afeat);

  // LSTM layer 1: MX-fp8, writes x_p/100 bf16 into feat
  gemm_lstm8<1><<<dim3(32, 29), 256, 0, stream>>>(
      A1f8, B1f8, c0 + (size_t)2*NH, bih1f, bhh1f,
      A1b8, B1b8, c0 + (size_t)3*NH, bih1b, bhh1b,
      Afeat, nullptr, NKT1, 16);

  // XW1^T = W1^T @ feat^T  split-K=4 (bf16)
  gemm_bt_sk<<<dim3(29, 4, 4), 256, 0, stream>>>(BW1, Afeat, xw1p, 1408, MP, 11);
  reduce_bf_pad<<<dim3(15, 512), 256, 0, stream>>>(xw1p, xwt1b, 4);

  // dense normalized adjacency (A1+xw1p dead)
  hipMemsetAsync(adjf, 0, (size_t)NN*KADJ*4, stream);
  adj_scatter<<<dim3((EE+NN+255)/256), 256, 0, stream>>>(ei, ei + EE, dinv, adjf);
  cvt_bf<<<dim3(15, MP), 256, 0, stream>>>(adjf, KADJ, adjb, NN, KADJ);

  // out1 = relu(Adj @ XW1 + b1) -> bf16, split-K=4
  gemm_bt_sk<<<dim3(4, 29, 4), 256, 0, stream>>>(adjb, xwt1b, h1p, KADJ, 512, 29);
  reduce_relu_bf<<<dim3(MP*512/256), 256, 0, stream>>>(h1p, b1, h1bf);

  // XW2^T = W2^T @ h1^T  split-K=4
  gemm_bt_sk<<<dim3(29, 2, 4), 256, 0, stream>>>(BW2, h1bf, xw2p, 512, MP, 4);
  reduce_bf_pad<<<dim3(15, 256), 256, 0, stream>>>(xw2p, xwt2b, 4);

  // out = Adj @ XW2 + b2, split-K=8
  gemm_bt_sk<<<dim3(2, 29, 8), 256, 0, stream>>>(adjb, xwt2b, o2p, KADJ, 256, 15);
  reduce_bias_out<<<dim3(3600), 256, 0, stream>>>(o2p, b2, outp);
}

// Round 7
// 332.548 us; speedup vs baseline: 2.7055x; 1.0267x over previous
//
#include <hip/hip_runtime.h>
#include <hip/hip_bf16.h>

#define NN 3600
#define MP 3712          // 29*128 padded rows
#define KADJ 3616        // 113*32 padded node-count for adjacency K
#define NH (3600*512)
#define EE 230400
#define NKT0 9           // L0 K = 1152 = 9*128 (588+512 padded)
#define NKT1 12          // L1 K = 1536 = 12*128

typedef __hip_bfloat16 bf16;
typedef __bf16 bf16x8 __attribute__((ext_vector_type(8)));
typedef float f32x4 __attribute__((ext_vector_type(4)));
typedef int i32x8 __attribute__((ext_vector_type(8)));
typedef unsigned char u8x16 __attribute__((ext_vector_type(16)));

typedef __attribute__((address_space(1))) void as1v;
typedef __attribute__((address_space(3))) void as3v;

__device__ __forceinline__ void glds16(void* lds, const void* g) {
  __builtin_amdgcn_global_load_lds((as1v*)(void*)g, (as3v*)lds, 16, 0, 0);
}

__device__ __forceinline__ float sigm(float v) { return 1.0f / (1.0f + expf(-v)); }

__device__ __forceinline__ unsigned char f2fp8(float f) {
  return (unsigned char)(__builtin_amdgcn_cvt_pk_fp8_f32(f, 0.f, 0, false) & 0xff);
}

// ---------------- MX-fp8 fused LSTM GEMM, counted-vmcnt pipeline -----------
// Operands tiled: [blk128][kt][kb:4][row:128][32B] fp8 e4m3, K-step = 128.
// B gate-interleaved: packed col R <-> gate (R>>4)&3, hidden ((R>>6)<<4)+(R&15).
// MODE 0: write h (fp8) into BOTH dst1/dst2 tiled-A1 buffers at k = kOff+jh.
// MODE 1: write h*0.01 (bf16) into Afeat row-major at col colOff+jh.
// Grid is ALWAYS (32, 29): XCD-chunk swizzle hardcoded for 928 = 8*116.
template<int MODE>
__global__ __launch_bounds__(256) void gemm_lstm8(
    const unsigned char* __restrict__ Af, const unsigned char* __restrict__ Bf,
    const float* __restrict__ c0f, const float* __restrict__ bihf,
    const float* __restrict__ bhhf,
    const unsigned char* __restrict__ Ab, const unsigned char* __restrict__ Bb,
    const float* __restrict__ c0b, const float* __restrict__ bihb,
    const float* __restrict__ bhhb,
    void* __restrict__ dst1, void* __restrict__ dst2,
    int nkt, int hx)
{
  __shared__ alignas(16) unsigned char smem[65536];   // 2 x (A 16KB | B 16KB)
  // XCD-aware bijective swizzle: id -> (xcd = id%8) gets contiguous chunk of 116
  const int id  = (int)blockIdx.y * 32 + (int)blockIdx.x;
  const int swz = (id & 7) * 116 + (id >> 3);
  const int bx  = swz & 31, by = swz >> 5;
  const bool back = bx >= hx;
  const unsigned char* A = back ? Ab : Af;
  const unsigned char* B = back ? Bb : Bf;
  const float* c0  = back ? c0b : c0f;
  const float* bih = back ? bihb : bihf;
  const float* bhh = back ? bhhb : bhhf;
  const int t = threadIdx.x, w = t >> 6, l = t & 63;
  const int nblk = back ? bx - hx : bx;
  const unsigned char* gA = A + (((size_t)by * nkt) << 14) + t*16;
  const unsigned char* gB = B + (((size_t)nblk * nkt) << 14) + t*16;
  const int wm = (w>>1)*64, wn = (w&1)*64;
  const int kb = l >> 4;
  const int aoff = kb*4096 + (wm + (l&15))*32;
  const int boff = 16384 + kb*4096 + (wn + (l&15))*32;
  f32x4 acc[4][4] = {};

  auto STAGE = [&](int buf, int kt) {
    unsigned char* lA = smem + buf*32768 + w*1024;
    unsigned char* lB = smem + buf*32768 + 16384 + w*1024;
    const size_t ko = (size_t)kt << 14;
    glds16(lA,          gA + ko);
    glds16(lA + 4096,   gA + ko + 4096);
    glds16(lA + 8192,   gA + ko + 8192);
    glds16(lA + 12288,  gA + ko + 12288);
    glds16(lB,          gB + ko);
    glds16(lB + 4096,   gB + ko + 4096);
    glds16(lB + 8192,   gB + ko + 8192);
    glds16(lB + 12288,  gB + ko + 12288);
  };

  STAGE(0, 0);
  STAGE(1, 1);                 // 16 loads in flight
  int cur = 0;
  for (int kt = 0; kt < nkt; ++kt) {
    // wait ONLY for tile kt's 8 loads (tile kt+1's 8 stay in flight)
    if (kt + 1 < nkt) asm volatile("s_waitcnt vmcnt(8)" ::: "memory");
    else              asm volatile("s_waitcnt vmcnt(0)" ::: "memory");
    __builtin_amdgcn_sched_barrier(0);
    __builtin_amdgcn_s_barrier();
    __builtin_amdgcn_sched_barrier(0);
    const unsigned char* base = smem + cur*32768;
    i32x8 av[4], bv[4];
#pragma unroll
    for (int mi = 0; mi < 4; ++mi) av[mi] = *(const i32x8*)(base + aoff + mi*512);
#pragma unroll
    for (int ni = 0; ni < 4; ++ni) bv[ni] = *(const i32x8*)(base + boff + ni*512);
#pragma unroll
    for (int mi = 0; mi < 4; ++mi)
#pragma unroll
      for (int ni = 0; ni < 4; ++ni)
        acc[mi][ni] = __builtin_amdgcn_mfma_scale_f32_16x16x128_f8f6f4(
            av[mi], bv[ni], acc[mi][ni], 0, 0, 0, 127, 0, 127);
    __builtin_amdgcn_sched_barrier(0);
    __builtin_amdgcn_s_barrier();      // all waves done reading buf[cur]
    __builtin_amdgcn_sched_barrier(0);
    if (kt + 2 < nkt) STAGE(cur, kt + 2);
    cur ^= 1;
  }
  // C/D layout: col = lane&15, row = (lane>>4)*4 + reg  [m89/m121-128]
  const int jh = (((nblk << 7) + wn) >> 2) + (l & 15);
  const float bI = bih[jh]        + bhh[jh];
  const float bF = bih[512 + jh]  + bhh[512 + jh];
  const float bG = bih[1024 + jh] + bhh[1024 + jh];
  const float bO = bih[1536 + jh] + bhh[1536 + jh];
  const int crow = (by << 7) + wm + ((l>>4)<<2);
  const int kk = (back ? 512 : 0) + jh;
  const size_t kpart = ((size_t)(kk >> 7) << 14) + ((size_t)((kk >> 5) & 3) << 12) + (kk & 31);
  const int colOff = back ? 896 : 384;
#pragma unroll
  for (int mi = 0; mi < 4; ++mi)
#pragma unroll
    for (int jr = 0; jr < 4; ++jr) {
      const int n = crow + mi*16 + jr;
      if (n < NN) {
        const float gi = acc[mi][0][jr] + bI;
        const float gf = acc[mi][1][jr] + bF;
        const float gg = acc[mi][2][jr] + bG;
        const float go = acc[mi][3][jr] + bO;
        const float c2 = sigm(gf) * c0[(size_t)n*512 + jh] + sigm(gi) * tanhf(gg);
        const float h  = sigm(go) * tanhf(c2);
        if (MODE == 0) {
          const unsigned char h8 = f2fp8(h);
          const size_t off = (((size_t)(n >> 7) * NKT1) << 14) + kpart + ((size_t)(n & 127) << 5);
          ((unsigned char*)dst1)[off] = h8;
          ((unsigned char*)dst2)[off] = h8;
        } else {
          ((bf16*)dst1)[(size_t)n*1408 + colOff + jh] = __float2bfloat16(h * 0.01f);
        }
      }
    }
}

// ---------------- split-K GEMM (bf16), counted-vmcnt pipeline ---------------
__global__ __launch_bounds__(256) void gemm_bt_sk(const bf16* __restrict__ A,
                                                  const bf16* __restrict__ B,
                                                  float* __restrict__ Cp,
                                                  int Kp, int ldc, int ksteps)
{
  __shared__ alignas(16) char smem[32768];   // 2 x (A 8KB | B 8KB)
  const int t = threadIdx.x, w = t >> 6, l = t & 63;
  const int mbase = blockIdx.y << 7, nbase = blockIdx.x << 7;
  const int total = Kp >> 5;
  const int kstart = blockIdx.z * ksteps;
  int steps = total - kstart; if (steps > ksteps) steps = ksteps;
  const size_t ldb = (size_t)Kp * 2;
  const char* gA = (const char*)A + (size_t)(mbase + w*16 + (l>>2)) * ldb
                   + (size_t)((l&3)*16) + (size_t)kstart*64;
  const char* gB = (const char*)B + (size_t)(nbase + w*16 + (l>>2)) * ldb
                   + (size_t)((l&3)*16) + (size_t)kstart*64;
  const int wm = (w>>1)*64, wn = (w&1)*64;
  const int aoff = (wm + (l&15))*64 + (l>>4)*16;
  const int boff = 8192 + (wn + (l&15))*64 + (l>>4)*16;
  f32x4 acc[4][4] = {};
  const size_t chunk = ldb * 64;

  auto STAGE = [&](int buf, int kt) {
    char* lA = smem + buf*16384 + w*1024;
    char* lB = smem + buf*16384 + 8192 + w*1024;
    const size_t ko = (size_t)kt * 64;
    glds16(lA,        gA + ko);
    glds16(lA + 4096, gA + ko + chunk);
    glds16(lB,        gB + ko);
    glds16(lB + 4096, gB + ko + chunk);
  };

  STAGE(0, 0);
  if (steps > 1) STAGE(1, 1);
  int cur = 0;
  for (int kt = 0; kt < steps; ++kt) {
    if (kt + 1 < steps) asm volatile("s_waitcnt vmcnt(4)" ::: "memory");
    else                asm volatile("s_waitcnt vmcnt(0)" ::: "memory");
    __builtin_amdgcn_sched_barrier(0);
    __builtin_amdgcn_s_barrier();
    __builtin_amdgcn_sched_barrier(0);
    const char* base = smem + cur*16384;
    bf16x8 av[4], bv[4];
#pragma unroll
    for (int mi = 0; mi < 4; ++mi) av[mi] = *(const bf16x8*)(base + aoff + mi*1024);
#pragma unroll
    for (int ni = 0; ni < 4; ++ni) bv[ni] = *(const bf16x8*)(base + boff + ni*1024);
#pragma unroll
    for (int mi = 0; mi < 4; ++mi)
#pragma unroll
      for (int ni = 0; ni < 4; ++ni)
        acc[mi][ni] = __builtin_amdgcn_mfma_f32_16x16x32_bf16(av[mi], bv[ni], acc[mi][ni], 0, 0, 0);
    __builtin_amdgcn_sched_barrier(0);
    __builtin_amdgcn_s_barrier();
    __builtin_amdgcn_sched_barrier(0);
    if (kt + 2 < steps) STAGE(cur, kt + 2);
    cur ^= 1;
  }
  float* Cz = Cp + (size_t)blockIdx.z * ((size_t)(gridDim.y << 7) * ldc);
  const int crow = mbase + wm + ((l>>4)<<2);
  const int ccol = nbase + wn + (l&15);
#pragma unroll
  for (int mi = 0; mi < 4; ++mi)
#pragma unroll
    for (int ni = 0; ni < 4; ++ni) {
      float* cp = Cz + (size_t)(crow + mi*16)*ldc + (ccol + ni*16);
#pragma unroll
      for (int j = 0; j < 4; ++j) cp[(size_t)j*ldc] = acc[mi][ni][j];
    }
}

// ---------------- reduce kernels ----------------
__global__ void reduce_bf_pad(const float* __restrict__ p, bf16* __restrict__ dst, int Z)
{
  int k = blockIdx.x*256 + threadIdx.x;
  int r = blockIdx.y;
  if (k >= KADJ) return;
  const size_t psz = (size_t)gridDim.y * MP;
  float s = 0.f;
  if (k < NN)
    for (int z = 0; z < Z; ++z) s += p[(size_t)z*psz + (size_t)r*MP + k];
  dst[(size_t)r*KADJ + k] = __float2bfloat16(s);
}

__global__ void reduce_relu_bf(const float* __restrict__ p, const float* __restrict__ b,
                               bf16* __restrict__ dst)
{
  int idx = blockIdx.x*256 + threadIdx.x;   // MP*512
  int f = idx & 511;
  float s = b[f];
#pragma unroll
  for (int z = 0; z < 4; ++z) s += p[(size_t)z*MP*512 + idx];
  dst[idx] = __float2bfloat16(fmaxf(s, 0.f));
}

__global__ void reduce_bias_out(const float* __restrict__ p, const float* __restrict__ b,
                                float* __restrict__ out)
{
  int idx = blockIdx.x*256 + threadIdx.x;   // NN*256
  if (idx >= NN*256) return;
  int f = idx & 255;
  float s = b[f];
#pragma unroll
  for (int z = 0; z < 8; ++z) s += p[(size_t)z*MP*256 + idx];
  out[idx] = s;
}

// ---------------- fp8 tiled packing ----------------
// dst layout: [blk128][kt][kb:4][r:128][32B]; thread t covers row t>>1, 16 bytes
__global__ void pack_B_8(const float* __restrict__ wih, const float* __restrict__ whh,
                         unsigned char* __restrict__ dst, int kx, int nkt)
{
  const int kt = blockIdx.x >> 2, kbId = blockIdx.x & 3;
  const int t = threadIdx.x;
  const int r = t >> 1, kio = (t & 1) << 4;
  const int R = ((int)blockIdx.y << 7) + r;
  const int src = (((R >> 4) & 3) << 9) + ((R >> 6) << 4) + (R & 15);
  const int kbase = kt*128 + kbId*32 + kio;
  u8x16 v;
#pragma unroll
  for (int i = 0; i < 16; ++i) {
    const int k = kbase + i;
    float f = 0.f;
    if (k < kx) f = wih[(size_t)src*kx + k];
    else if (k < kx + 512) f = whh[(size_t)src*512 + (k - kx)];
    v[i] = f2fp8(f);
  }
  *(u8x16*)(dst + (((size_t)blockIdx.y*nkt + kt) << 14) + (kbId << 12) + (r << 5) + kio) = v;
}

__global__ void pack_A0_8(const float* __restrict__ x, const float* __restrict__ h0,
                          unsigned char* __restrict__ a0f, unsigned char* __restrict__ a0b)
{
  const int kt = blockIdx.x >> 2, kbId = blockIdx.x & 3;
  const int t = threadIdx.x;
  const int r = t >> 1, kio = (t & 1) << 4;
  const int n = ((int)blockIdx.y << 7) + r;
  const int kbase = kt*128 + kbId*32 + kio;
  const float* hsrc = h0 + (size_t)blockIdx.z * NH;
  u8x16 v;
#pragma unroll
  for (int i = 0; i < 16; ++i) {
    const int k = kbase + i;
    float f = 0.f;
    if (n < NN) {
      if (k < 588) f = x[(size_t)n*972 + k];
      else if (k < 1100) f = hsrc[(size_t)n*512 + (k - 588)];
    }
    v[i] = f2fp8(f);
  }
  unsigned char* dst = blockIdx.z ? a0b : a0f;
  *(u8x16*)(dst + (((size_t)blockIdx.y*NKT0 + kt) << 14) + (kbId << 12) + (r << 5) + kio) = v;
}

__global__ void pack_A1h_8(const float* __restrict__ h0,
                           unsigned char* __restrict__ a1f, unsigned char* __restrict__ a1b)
{
  const int kt = 8 + (blockIdx.x >> 2), kbId = blockIdx.x & 3;
  const int t = threadIdx.x;
  const int r = t >> 1, kio = (t & 1) << 4;
  const int n = ((int)blockIdx.y << 7) + r;
  const int kbase = kt*128 + kbId*32 + kio;
  const float* hsrc = h0 + (size_t)(2 + blockIdx.z) * NH;
  u8x16 v;
#pragma unroll
  for (int i = 0; i < 16; ++i) {
    const int k = kbase + i;
    float f = (n < NN) ? hsrc[(size_t)n*512 + (k - 1024)] : 0.f;
    v[i] = f2fp8(f);
  }
  unsigned char* dst = blockIdx.z ? a1b : a1f;
  *(u8x16*)(dst + (((size_t)blockIdx.y*NKT1 + kt) << 14) + (kbId << 12) + (r << 5) + kio) = v;
}

// ---------------- bf16 packing (GCN path) ----------------
__global__ void pack_BT(const float* __restrict__ W, bf16* __restrict__ dst, int Nc, int K)
{
  int k = blockIdx.x*256 + threadIdx.x;
  int n = blockIdx.y;
  if (k >= K) return;
  dst[(size_t)n*K + k] = __float2bfloat16(W[(size_t)k*Nc + n]);
}

__global__ void pack_prot(const float* __restrict__ x, bf16* __restrict__ afeat)
{
  int k = blockIdx.x*256 + threadIdx.x;    // [0,384)
  int n = blockIdx.y;
  if (k >= 384) return;
  float v = (n < NN) ? x[(size_t)n*972 + 588 + k] : 0.f;
  afeat[(size_t)n*1408 + k] = __float2bfloat16(v);
}

// ---------------- degree / norm ----------------
__global__ void deg_count(const int* __restrict__ ecols, int* __restrict__ deg)
{
  int e = blockIdx.x*256 + threadIdx.x;
  if (e < EE) atomicAdd(&deg[ecols[e]], 1);
}

__global__ void calc_dinv(const int* __restrict__ deg, float* __restrict__ dinv)
{
  int n = blockIdx.x*256 + threadIdx.x;
  if (n < NN) dinv[n] = 1.0f / sqrtf((float)(deg[n] + 1));
}

// ---------------- dense normalized adjacency build ----------------
__global__ void adj_scatter(const int* __restrict__ er, const int* __restrict__ ec,
                            const float* __restrict__ dinv, float* __restrict__ adjf)
{
  int e = blockIdx.x*256 + threadIdx.x;
  if (e < EE) {
    int r = er[e], c = ec[e];
    atomicAdd(&adjf[(size_t)c*KADJ + r], dinv[r]*dinv[c]);
  } else if (e < EE + NN) {
    int n = e - EE;
    float d = dinv[n];
    atomicAdd(&adjf[(size_t)n*KADJ + n], d*d);
  }
}

__global__ void cvt_bf(const float* __restrict__ src, int lds,
                       bf16* __restrict__ dst, int rv, int kv)
{
  int k = blockIdx.x*256 + threadIdx.x;
  int r = blockIdx.y;
  if (k >= KADJ) return;
  float v = (r < rv && k < kv) ? src[(size_t)r*lds + k] : 0.f;
  dst[(size_t)r*KADJ + k] = __float2bfloat16(v);
}

// ---------------- workspace layout (bytes), total <= 93,339,648 (proven) ----
#define OFF_DEG   ((size_t)0)
#define OFF_DINV  ((size_t)16384)
#define OFF_BW2   ((size_t)32768)
#define OFF_B0F   ((size_t)294912)     // fp8: 2,359,296
#define OFF_B0B   ((size_t)4882432)
#define OFF_B1F   ((size_t)9469952)    // fp8: 3,145,728
#define OFF_B1B   ((size_t)15761408)
#define OFF_BW1   ((size_t)22052864)
#define OFF_A0F   ((size_t)23494656)   // fp8: 4,276,224
#define OFF_A0B   ((size_t)31809536)
#define OFF_A1F   ((size_t)40124416)   // fp8: 5,701,632
#define OFF_A1B   ((size_t)51527680)
#define OFF_G     ((size_t)62930944)
// ---- overlays (temporal reuse) ----
#define OFF_AFEAT OFF_A0F              // alive: pack_prot .. xwt1 gemm
#define OFF_XW1P  OFF_G                // xwt1 partials 30,408,704
#define OFF_XWT1B OFF_B0F              // 3,702,784 (B0 dead after L0)
#define OFF_ADJF  ((size_t)40124416)   // 52,070,400 (A1+xw1p dead after xwt1+reduce)
#define OFF_ADJB  ((size_t)4194304)    // 26,845,184 (B0b/B1/BW1/Afeat dead)
#define OFF_H1P   ((size_t)40124416)   // agg1 partials (adjf dead)
#define OFF_H1    ((size_t)70533120)
#define OFF_XW2P  ((size_t)74334208)
#define OFF_XWT2B ((size_t)89538560)
#define OFF_O2P   ((size_t)40124416)   // agg2 partials (h1p dead)

extern "C" void kernel_launch(void* const* d_in, const int* in_sizes, int n_in,
                              void* d_out, int out_size, void* d_ws, size_t ws_size,
                              hipStream_t stream)
{
  const float* x    = (const float*)d_in[0];
  const int*   ei   = (const int*)d_in[1];
  const float* h0   = (const float*)d_in[2];
  const float* c0   = (const float*)d_in[3];
  const float* wih0f = (const float*)d_in[4];
  const float* whh0f = (const float*)d_in[5];
  const float* bih0f = (const float*)d_in[6];
  const float* bhh0f = (const float*)d_in[7];
  const float* wih0b = (const float*)d_in[8];
  const float* whh0b = (const float*)d_in[9];
  const float* bih0b = (const float*)d_in[10];
  const float* bhh0b = (const float*)d_in[11];
  const float* wih1f = (const float*)d_in[12];
  const float* whh1f = (const float*)d_in[13];
  const float* bih1f = (const float*)d_in[14];
  const float* bhh1f = (const float*)d_in[15];
  const float* wih1b = (const float*)d_in[16];
  const float* whh1b = (const float*)d_in[17];
  const float* bih1b = (const float*)d_in[18];
  const float* bhh1b = (const float*)d_in[19];
  const float* W1 = (const float*)d_in[20];
  const float* b1 = (const float*)d_in[21];
  const float* W2 = (const float*)d_in[22];
  const float* b2 = (const float*)d_in[23];

  char* ws = (char*)d_ws;
  int*   deg  = (int*)(ws + OFF_DEG);
  float* dinv = (float*)(ws + OFF_DINV);
  unsigned char* B0f8 = (unsigned char*)(ws + OFF_B0F);
  unsigned char* B0b8 = (unsigned char*)(ws + OFF_B0B);
  unsigned char* B1f8 = (unsigned char*)(ws + OFF_B1F);
  unsigned char* B1b8 = (unsigned char*)(ws + OFF_B1B);
  bf16* BW1 = (bf16*)(ws + OFF_BW1);
  bf16* BW2 = (bf16*)(ws + OFF_BW2);
  unsigned char* A0f8 = (unsigned char*)(ws + OFF_A0F);
  unsigned char* A0b8 = (unsigned char*)(ws + OFF_A0B);
  unsigned char* A1f8 = (unsigned char*)(ws + OFF_A1F);
  unsigned char* A1b8 = (unsigned char*)(ws + OFF_A1B);
  bf16* Afeat = (bf16*)(ws + OFF_AFEAT);
  float* xw1p  = (float*)(ws + OFF_XW1P);
  bf16*  xwt1b = (bf16*)(ws + OFF_XWT1B);
  float* adjf  = (float*)(ws + OFF_ADJF);
  bf16*  adjb  = (bf16*)(ws + OFF_ADJB);
  float* h1p   = (float*)(ws + OFF_H1P);
  bf16*  h1bf  = (bf16*)(ws + OFF_H1);
  float* xw2p  = (float*)(ws + OFF_XW2P);
  bf16*  xwt2b = (bf16*)(ws + OFF_XWT2B);
  float* o2p   = (float*)(ws + OFF_O2P);
  float* outp = (float*)d_out;

  // degree + norm
  hipMemsetAsync(deg, 0, (size_t)NN*4, stream);
  deg_count<<<dim3((EE+255)/256), 256, 0, stream>>>(ei + EE, deg);
  calc_dinv<<<dim3(15), 256, 0, stream>>>(deg, dinv);

  // weight packing: fp8 tiled (LSTM), bf16 (GCN)
  pack_B_8<<<dim3(NKT0*4, 16), 256, 0, stream>>>(wih0f, whh0f, B0f8, 588, NKT0);
  pack_B_8<<<dim3(NKT0*4, 16), 256, 0, stream>>>(wih0b, whh0b, B0b8, 588, NKT0);
  pack_B_8<<<dim3(NKT1*4, 16), 256, 0, stream>>>(wih1f, whh1f, B1f8, 1024, NKT1);
  pack_B_8<<<dim3(NKT1*4, 16), 256, 0, stream>>>(wih1b, whh1b, B1b8, 1024, NKT1);
  pack_BT<<<dim3(6, 512), 256, 0, stream>>>(W1, BW1, 512, 1408);
  pack_BT<<<dim3(2, 256), 256, 0, stream>>>(W2, BW2, 256, 512);

  // activations packing (fp8 tiled)
  pack_A0_8<<<dim3(NKT0*4, 29, 2), 256, 0, stream>>>(x, h0, A0f8, A0b8);
  pack_A1h_8<<<dim3(16, 29, 2), 256, 0, stream>>>(h0, A1f8, A1b8);

  // LSTM layer 0: MX-fp8, merged f+b, gate fused; writes x1 fp8 into A1f/A1b
  gemm_lstm8<0><<<dim3(32, 29), 256, 0, stream>>>(
      A0f8, B0f8, c0,              bih0f, bhh0f,
      A0b8, B0b8, c0 + (size_t)NH, bih0b, bhh0b,
      A1f8, A1b8, NKT0, 16);

  // feat: prot part (A0 dead; Afeat overlays it)
  pack_prot<<<dim3(2, MP), 256, 0, stream>>>(x, Afeat);

  // LSTM layer 1: MX-fp8, writes x_p/100 bf16 into feat
  gemm_lstm8<1><<<dim3(32, 29), 256, 0, stream>>>(
      A1f8, B1f8, c0 + (size_t)2*NH, bih1f, bhh1f,
      A1b8, B1b8, c0 + (size_t)3*NH, bih1b, bhh1b,
      Afeat, nullptr, NKT1, 16);

  // XW1^T = W1^T @ feat^T  split-K=4 (bf16)
  gemm_bt_sk<<<dim3(29, 4, 4), 256, 0, stream>>>(BW1, Afeat, xw1p, 1408, MP, 11);
  reduce_bf_pad<<<dim3(15, 512), 256, 0, stream>>>(xw1p, xwt1b, 4);

  // dense normalized adjacency (A1+xw1p dead)
  hipMemsetAsync(adjf, 0, (size_t)NN*KADJ*4, stream);
  adj_scatter<<<dim3((EE+NN+255)/256), 256, 0, stream>>>(ei, ei + EE, dinv, adjf);
  cvt_bf<<<dim3(15, MP), 256, 0, stream>>>(adjf, KADJ, adjb, NN, KADJ);

  // out1 = relu(Adj @ XW1 + b1) -> bf16, split-K=4
  gemm_bt_sk<<<dim3(4, 29, 4), 256, 0, stream>>>(adjb, xwt1b, h1p, KADJ, 512, 29);
  reduce_relu_bf<<<dim3(MP*512/256), 256, 0, stream>>>(h1p, b1, h1bf);

  // XW2^T = W2^T @ h1^T  split-K=4
  gemm_bt_sk<<<dim3(29, 2, 4), 256, 0, stream>>>(BW2, h1bf, xw2p, 512, MP, 4);
  reduce_bf_pad<<<dim3(15, 256), 256, 0, stream>>>(xw2p, xwt2b, 4);

  // out = Adj @ XW2 + b2, split-K=8
  gemm_bt_sk<<<dim3(2, 29, 8), 256, 0, stream>>>(adjb, xwt2b, o2p, KADJ, 256, 15);
  reduce_bias_out<<<dim3(3600), 256, 0, stream>>>(o2p, b2, outp);
}

// Round 8
// 329.478 us; speedup vs baseline: 2.7307x; 1.0093x over previous
//
#include <hip/hip_runtime.h>
#include <hip/hip_bf16.h>

#define NN 3600
#define MP 3712          // 29*128 padded rows
#define KADJ 3616        // 113*32 padded node-count for adjacency K
#define NH (3600*512)
#define EE 230400
#define NKT0 9           // L0 K = 1152 = 9*128 (588+512 padded)
#define NKT1 12          // L1 K = 1536 = 12*128 (1024 x1 + 512 h0)

typedef __hip_bfloat16 bf16;
typedef __bf16 bf16x8 __attribute__((ext_vector_type(8)));
typedef float f32x4 __attribute__((ext_vector_type(4)));
typedef int i32x8 __attribute__((ext_vector_type(8)));
typedef unsigned char u8x16 __attribute__((ext_vector_type(16)));

typedef __attribute__((address_space(1))) void as1v;
typedef __attribute__((address_space(3))) void as3v;

__device__ __forceinline__ void glds16(void* lds, const void* g) {
  __builtin_amdgcn_global_load_lds((as1v*)(void*)g, (as3v*)lds, 16, 0, 0);
}

__device__ __forceinline__ float sigm(float v) { return 1.0f / (1.0f + expf(-v)); }

__device__ __forceinline__ unsigned char f2fp8(float f) {
  return (unsigned char)(__builtin_amdgcn_cvt_pk_fp8_f32(f, 0.f, 0, false) & 0xff);
}

// ---------------- MX-fp8 fused LSTM GEMM, counted-vmcnt + rect-XCD ---------
// Operands tiled: [blk128][kt][kb:4][row:128][32B] fp8 e4m3, K-step = 128.
// A split: kt < nktx from Ax (per-dir or shared), kt >= nktx from Ah (per-dir).
// B gate-interleaved: packed col R <-> gate (R>>4)&3, hidden ((R>>6)<<4)+(R&15).
// MODE 0: write h (fp8) into tiled A1X (nkt=8 stride) at k = dirOff+jh.
// MODE 1: write h*0.01 (bf16) into Afeat row-major at col colOff+jh.
// Grid ALWAYS (32, 29): rect-XCD map hardcoded (8 rects of 8bx x 14by + row 28).
template<int MODE>
__global__ __launch_bounds__(256) void gemm_lstm8(
    const unsigned char* __restrict__ Axf, const unsigned char* __restrict__ Ahf,
    const unsigned char* __restrict__ Bf,
    const float* __restrict__ c0f, const float* __restrict__ bihf,
    const float* __restrict__ bhhf,
    const unsigned char* __restrict__ Axb, const unsigned char* __restrict__ Ahb,
    const unsigned char* __restrict__ Bb,
    const float* __restrict__ c0b, const float* __restrict__ bihb,
    const float* __restrict__ bhhb,
    void* __restrict__ dst1,
    int nktx, int nkt, int hx)
{
  __shared__ alignas(16) unsigned char smem[65536];   // 2 x (A 16KB | B 16KB)
  // rect-XCD bijection: xcd = hid%8 owns bx in [8*(xcd&3), +8), by in [14*(xcd>>2), +14)
  // plus 4 blocks of the by=28 remainder row.
  const int hid = (int)blockIdx.y * 32 + (int)blockIdx.x;
  const int xcd = hid & 7, idx = hid >> 3;
  int bx, by;
  if (idx < 112) { bx = (xcd & 3) * 8 + (idx & 7); by = (xcd >> 2) * 14 + (idx >> 3); }
  else { int k = idx - 112; bx = (xcd & 3) * 8 + k * 2 + (xcd >> 2); by = 28; }
  const bool back = bx >= hx;
  const unsigned char* Ax = back ? Axb : Axf;
  const unsigned char* Ah = back ? Ahb : Ahf;
  const unsigned char* B  = back ? Bb  : Bf;
  const float* c0  = back ? c0b : c0f;
  const float* bih = back ? bihb : bihf;
  const float* bhh = back ? bhhb : bhhf;
  const int t = threadIdx.x, w = t >> 6, l = t & 63;
  const int nblk = back ? bx - hx : bx;
  const unsigned char* gA  = Ax + (((size_t)by * nktx) << 14) + t*16;
  const unsigned char* gAh = Ah + (((size_t)by * (nkt - nktx)) << 14) + t*16;
  const unsigned char* gB  = B  + (((size_t)nblk * nkt) << 14) + t*16;
  const int wm = (w>>1)*64, wn = (w&1)*64;
  const int kb = l >> 4;
  const int aoff = kb*4096 + (wm + (l&15))*32;
  const int boff = 16384 + kb*4096 + (wn + (l&15))*32;
  f32x4 acc[4][4] = {};

  auto STAGE = [&](int buf, int kt) {
    unsigned char* lA = smem + buf*32768 + w*1024;
    unsigned char* lB = smem + buf*32768 + 16384 + w*1024;
    const unsigned char* srcA = (kt < nktx) ? gA + ((size_t)kt << 14)
                                            : gAh + ((size_t)(kt - nktx) << 14);
    const size_t ko = (size_t)kt << 14;
    glds16(lA,          srcA);
    glds16(lA + 4096,   srcA + 4096);
    glds16(lA + 8192,   srcA + 8192);
    glds16(lA + 12288,  srcA + 12288);
    glds16(lB,          gB + ko);
    glds16(lB + 4096,   gB + ko + 4096);
    glds16(lB + 8192,   gB + ko + 8192);
    glds16(lB + 12288,  gB + ko + 12288);
  };

  STAGE(0, 0);
  STAGE(1, 1);                 // 16 loads in flight
  int cur = 0;
  for (int kt = 0; kt < nkt; ++kt) {
    if (kt + 1 < nkt) asm volatile("s_waitcnt vmcnt(8)" ::: "memory");
    else              asm volatile("s_waitcnt vmcnt(0)" ::: "memory");
    __builtin_amdgcn_sched_barrier(0);
    __builtin_amdgcn_s_barrier();
    __builtin_amdgcn_sched_barrier(0);
    const unsigned char* base = smem + cur*32768;
    i32x8 av[4], bv[4];
#pragma unroll
    for (int mi = 0; mi < 4; ++mi) av[mi] = *(const i32x8*)(base + aoff + mi*512);
#pragma unroll
    for (int ni = 0; ni < 4; ++ni) bv[ni] = *(const i32x8*)(base + boff + ni*512);
#pragma unroll
    for (int mi = 0; mi < 4; ++mi)
#pragma unroll
      for (int ni = 0; ni < 4; ++ni)
        acc[mi][ni] = __builtin_amdgcn_mfma_scale_f32_16x16x128_f8f6f4(
            av[mi], bv[ni], acc[mi][ni], 0, 0, 0, 127, 0, 127);
    __builtin_amdgcn_sched_barrier(0);
    __builtin_amdgcn_s_barrier();      // all waves done reading buf[cur]
    __builtin_amdgcn_sched_barrier(0);
    if (kt + 2 < nkt) STAGE(cur, kt + 2);
    cur ^= 1;
  }
  // C/D layout: col = lane&15, row = (lane>>4)*4 + reg  [m89/m121-128]
  const int jh = (((nblk << 7) + wn) >> 2) + (l & 15);
  const float bI = bih[jh]        + bhh[jh];
  const float bF = bih[512 + jh]  + bhh[512 + jh];
  const float bG = bih[1024 + jh] + bhh[1024 + jh];
  const float bO = bih[1536 + jh] + bhh[1536 + jh];
  const int crow = (by << 7) + wm + ((l>>4)<<2);
  const int kk = (back ? 512 : 0) + jh;            // col in x1 (0..1023)
  const size_t kpart = ((size_t)(kk >> 7) << 14) + ((size_t)((kk >> 5) & 3) << 12) + (kk & 31);
  const int colOff = back ? 896 : 384;
#pragma unroll
  for (int mi = 0; mi < 4; ++mi)
#pragma unroll
    for (int jr = 0; jr < 4; ++jr) {
      const int n = crow + mi*16 + jr;
      if (n < NN) {
        const float gi = acc[mi][0][jr] + bI;
        const float gf = acc[mi][1][jr] + bF;
        const float gg = acc[mi][2][jr] + bG;
        const float go = acc[mi][3][jr] + bO;
        const float c2 = sigm(gf) * c0[(size_t)n*512 + jh] + sigm(gi) * tanhf(gg);
        const float h  = sigm(go) * tanhf(c2);
        if (MODE == 0) {
          // A1X tiled with nkt=8 (x1 part only)
          const size_t off = (((size_t)(n >> 7) * 8) << 14) + kpart + ((size_t)(n & 127) << 5);
          ((unsigned char*)dst1)[off] = f2fp8(h);
        } else {
          ((bf16*)dst1)[(size_t)n*1408 + colOff + jh] = __float2bfloat16(h * 0.01f);
        }
      }
    }
}

// ---------------- split-K GEMM (bf16), counted-vmcnt pipeline ---------------
__global__ __launch_bounds__(256) void gemm_bt_sk(const bf16* __restrict__ A,
                                                  const bf16* __restrict__ B,
                                                  float* __restrict__ Cp,
                                                  int Kp, int ldc, int ksteps)
{
  __shared__ alignas(16) char smem[32768];   // 2 x (A 8KB | B 8KB)
  const int t = threadIdx.x, w = t >> 6, l = t & 63;
  const int mbase = blockIdx.y << 7, nbase = blockIdx.x << 7;
  const int total = Kp >> 5;
  const int kstart = blockIdx.z * ksteps;
  int steps = total - kstart; if (steps > ksteps) steps = ksteps;
  const size_t ldb = (size_t)Kp * 2;
  const char* gA = (const char*)A + (size_t)(mbase + w*16 + (l>>2)) * ldb
                   + (size_t)((l&3)*16) + (size_t)kstart*64;
  const char* gB = (const char*)B + (size_t)(nbase + w*16 + (l>>2)) * ldb
                   + (size_t)((l&3)*16) + (size_t)kstart*64;
  const int wm = (w>>1)*64, wn = (w&1)*64;
  const int aoff = (wm + (l&15))*64 + (l>>4)*16;
  const int boff = 8192 + (wn + (l&15))*64 + (l>>4)*16;
  f32x4 acc[4][4] = {};
  const size_t chunk = ldb * 64;

  auto STAGE = [&](int buf, int kt) {
    char* lA = smem + buf*16384 + w*1024;
    char* lB = smem + buf*16384 + 8192 + w*1024;
    const size_t ko = (size_t)kt * 64;
    glds16(lA,        gA + ko);
    glds16(lA + 4096, gA + ko + chunk);
    glds16(lB,        gB + ko);
    glds16(lB + 4096, gB + ko + chunk);
  };

  STAGE(0, 0);
  if (steps > 1) STAGE(1, 1);
  int cur = 0;
  for (int kt = 0; kt < steps; ++kt) {
    if (kt + 1 < steps) asm volatile("s_waitcnt vmcnt(4)" ::: "memory");
    else                asm volatile("s_waitcnt vmcnt(0)" ::: "memory");
    __builtin_amdgcn_sched_barrier(0);
    __builtin_amdgcn_s_barrier();
    __builtin_amdgcn_sched_barrier(0);
    const char* base = smem + cur*16384;
    bf16x8 av[4], bv[4];
#pragma unroll
    for (int mi = 0; mi < 4; ++mi) av[mi] = *(const bf16x8*)(base + aoff + mi*1024);
#pragma unroll
    for (int ni = 0; ni < 4; ++ni) bv[ni] = *(const bf16x8*)(base + boff + ni*1024);
#pragma unroll
    for (int mi = 0; mi < 4; ++mi)
#pragma unroll
      for (int ni = 0; ni < 4; ++ni)
        acc[mi][ni] = __builtin_amdgcn_mfma_f32_16x16x32_bf16(av[mi], bv[ni], acc[mi][ni], 0, 0, 0);
    __builtin_amdgcn_sched_barrier(0);
    __builtin_amdgcn_s_barrier();
    __builtin_amdgcn_sched_barrier(0);
    if (kt + 2 < steps) STAGE(cur, kt + 2);
    cur ^= 1;
  }
  float* Cz = Cp + (size_t)blockIdx.z * ((size_t)(gridDim.y << 7) * ldc);
  const int crow = mbase + wm + ((l>>4)<<2);
  const int ccol = nbase + wn + (l&15);
#pragma unroll
  for (int mi = 0; mi < 4; ++mi)
#pragma unroll
    for (int ni = 0; ni < 4; ++ni) {
      float* cp = Cz + (size_t)(crow + mi*16)*ldc + (ccol + ni*16);
#pragma unroll
      for (int j = 0; j < 4; ++j) cp[(size_t)j*ldc] = acc[mi][ni][j];
    }
}

// ---------------- reduce kernels ----------------
__global__ void reduce_bf_pad(const float* __restrict__ p, bf16* __restrict__ dst, int Z)
{
  int k = blockIdx.x*256 + threadIdx.x;
  int r = blockIdx.y;
  if (k >= KADJ) return;
  const size_t psz = (size_t)gridDim.y * MP;
  float s = 0.f;
  if (k < NN)
    for (int z = 0; z < Z; ++z) s += p[(size_t)z*psz + (size_t)r*MP + k];
  dst[(size_t)r*KADJ + k] = __float2bfloat16(s);
}

__global__ void reduce_relu_bf(const float* __restrict__ p, const float* __restrict__ b,
                               bf16* __restrict__ dst)
{
  int idx = blockIdx.x*256 + threadIdx.x;   // MP*512
  int f = idx & 511;
  float s = b[f];
#pragma unroll
  for (int z = 0; z < 4; ++z) s += p[(size_t)z*MP*512 + idx];
  dst[idx] = __float2bfloat16(fmaxf(s, 0.f));
}

__global__ void reduce_bias_out(const float* __restrict__ p, const float* __restrict__ b,
                                float* __restrict__ out)
{
  int idx = blockIdx.x*256 + threadIdx.x;   // NN*256
  if (idx >= NN*256) return;
  int f = idx & 255;
  float s = b[f];
#pragma unroll
  for (int z = 0; z < 8; ++z) s += p[(size_t)z*MP*256 + idx];
  out[idx] = s;
}

// ---------------- fp8 tiled packing ----------------
// dst layout: [blk128][kt][kb:4][r:128][32B]; thread t covers row t>>1, 16 bytes
__global__ void pack_B_8(const float* __restrict__ wih, const float* __restrict__ whh,
                         unsigned char* __restrict__ dst, int kx, int nkt)
{
  const int kt = blockIdx.x >> 2, kbId = blockIdx.x & 3;
  const int t = threadIdx.x;
  const int r = t >> 1, kio = (t & 1) << 4;
  const int R = ((int)blockIdx.y << 7) + r;
  const int src = (((R >> 4) & 3) << 9) + ((R >> 6) << 4) + (R & 15);
  const int kbase = kt*128 + kbId*32 + kio;
  u8x16 v;
#pragma unroll
  for (int i = 0; i < 16; ++i) {
    const int k = kbase + i;
    float f = 0.f;
    if (k < kx) f = wih[(size_t)src*kx + k];
    else if (k < kx + 512) f = whh[(size_t)src*512 + (k - kx)];
    v[i] = f2fp8(f);
  }
  *(u8x16*)(dst + (((size_t)blockIdx.y*nkt + kt) << 14) + (kbId << 12) + (r << 5) + kio) = v;
}

__global__ void pack_A0_8(const float* __restrict__ x, const float* __restrict__ h0,
                          unsigned char* __restrict__ a0f, unsigned char* __restrict__ a0b)
{
  const int kt = blockIdx.x >> 2, kbId = blockIdx.x & 3;
  const int t = threadIdx.x;
  const int r = t >> 1, kio = (t & 1) << 4;
  const int n = ((int)blockIdx.y << 7) + r;
  const int kbase = kt*128 + kbId*32 + kio;
  const float* hsrc = h0 + (size_t)blockIdx.z * NH;
  u8x16 v;
#pragma unroll
  for (int i = 0; i < 16; ++i) {
    const int k = kbase + i;
    float f = 0.f;
    if (n < NN) {
      if (k < 588) f = x[(size_t)n*972 + k];
      else if (k < 1100) f = hsrc[(size_t)n*512 + (k - 588)];
    }
    v[i] = f2fp8(f);
  }
  unsigned char* dst = blockIdx.z ? a0b : a0f;
  *(u8x16*)(dst + (((size_t)blockIdx.y*NKT0 + kt) << 14) + (kbId << 12) + (r << 5) + kio) = v;
}

// h0-tail of L1 A: 4 kt per direction, local kt 0..3 (k in [1024,1536))
__global__ void pack_A1h_8(const float* __restrict__ h0,
                           unsigned char* __restrict__ ahf, unsigned char* __restrict__ ahb)
{
  const int ktl = blockIdx.x >> 2, kbId = blockIdx.x & 3;   // ktl 0..3
  const int t = threadIdx.x;
  const int r = t >> 1, kio = (t & 1) << 4;
  const int n = ((int)blockIdx.y << 7) + r;
  const int kbase = ktl*128 + kbId*32 + kio;                // k-1024
  const float* hsrc = h0 + (size_t)(2 + blockIdx.z) * NH;
  u8x16 v;
#pragma unroll
  for (int i = 0; i < 16; ++i) {
    const int k = kbase + i;
    float f = (n < NN) ? hsrc[(size_t)n*512 + k] : 0.f;
    v[i] = f2fp8(f);
  }
  unsigned char* dst = blockIdx.z ? ahb : ahf;
  *(u8x16*)(dst + (((size_t)blockIdx.y*4 + ktl) << 14) + (kbId << 12) + (r << 5) + kio) = v;
}

// ---------------- bf16 packing (GCN path) ----------------
__global__ void pack_BT(const float* __restrict__ W, bf16* __restrict__ dst, int Nc, int K)
{
  int k = blockIdx.x*256 + threadIdx.x;
  int n = blockIdx.y;
  if (k >= K) return;
  dst[(size_t)n*K + k] = __float2bfloat16(W[(size_t)k*Nc + n]);
}

__global__ void pack_prot(const float* __restrict__ x, bf16* __restrict__ afeat)
{
  int k = blockIdx.x*256 + threadIdx.x;    // [0,384)
  int n = blockIdx.y;
  if (k >= 384) return;
  float v = (n < NN) ? x[(size_t)n*972 + 588 + k] : 0.f;
  afeat[(size_t)n*1408 + k] = __float2bfloat16(v);
}

// ---------------- degree / norm ----------------
__global__ void deg_count(const int* __restrict__ ecols, int* __restrict__ deg)
{
  int e = blockIdx.x*256 + threadIdx.x;
  if (e < EE) atomicAdd(&deg[ecols[e]], 1);
}

__global__ void calc_dinv(const int* __restrict__ deg, float* __restrict__ dinv)
{
  int n = blockIdx.x*256 + threadIdx.x;
  if (n < NN) dinv[n] = 1.0f / sqrtf((float)(deg[n] + 1));
}

// ---------------- dense normalized adjacency build ----------------
__global__ void adj_scatter(const int* __restrict__ er, const int* __restrict__ ec,
                            const float* __restrict__ dinv, float* __restrict__ adjf)
{
  int e = blockIdx.x*256 + threadIdx.x;
  if (e < EE) {
    int r = er[e], c = ec[e];
    atomicAdd(&adjf[(size_t)c*KADJ + r], dinv[r]*dinv[c]);
  } else if (e < EE + NN) {
    int n = e - EE;
    float d = dinv[n];
    atomicAdd(&adjf[(size_t)n*KADJ + n], d*d);
  }
}

__global__ void cvt_bf(const float* __restrict__ src, int lds,
                       bf16* __restrict__ dst, int rv, int kv)
{
  int k = blockIdx.x*256 + threadIdx.x;
  int r = blockIdx.y;
  if (k >= KADJ) return;
  float v = (r < rv && k < kv) ? src[(size_t)r*lds + k] : 0.f;
  dst[(size_t)r*KADJ + k] = __float2bfloat16(v);
}

// ---------------- workspace layout (bytes), total <= 93,339,648 (proven) ----
#define OFF_DEG   ((size_t)0)
#define OFF_DINV  ((size_t)16384)
#define OFF_BW2   ((size_t)32768)
#define OFF_B0F   ((size_t)294912)     // fp8: 2,359,296
#define OFF_B0B   ((size_t)4882432)
#define OFF_B1F   ((size_t)9469952)    // fp8: 3,145,728
#define OFF_B1B   ((size_t)15761408)
#define OFF_BW1   ((size_t)22052864)
#define OFF_A0F   ((size_t)23494656)   // fp8: 4,276,224
#define OFF_A0B   ((size_t)31809536)
#define OFF_A1X   ((size_t)40124416)   // shared x1, nkt=8: 3,801,088
#define OFF_A1HF  ((size_t)43925504)   // h0 tail fwd, 4kt: 1,900,544
#define OFF_A1HB  ((size_t)45826048)   // h0 tail bwd: 1,900,544 -> 47,726,592
#define OFF_G     ((size_t)62930944)
// ---- overlays (temporal reuse) ----
#define OFF_AFEAT OFF_A0F              // alive: pack_prot .. xwt1 gemm
#define OFF_XW1P  OFF_G                // xwt1 partials 30,408,704
#define OFF_XWT1B OFF_B0F              // 3,702,784 (B0 dead after L0)
#define OFF_ADJF  ((size_t)40124416)   // 52,070,400 (A1+xw1p dead after xwt1+reduce)
#define OFF_ADJB  ((size_t)4194304)    // 26,845,184 (B0b/B1/BW1/Afeat dead)
#define OFF_H1P   ((size_t)40124416)   // agg1 partials (adjf dead)
#define OFF_H1    ((size_t)70533120)
#define OFF_XW2P  ((size_t)74334208)
#define OFF_XWT2B ((size_t)89538560)
#define OFF_O2P   ((size_t)40124416)   // agg2 partials (h1p dead)

extern "C" void kernel_launch(void* const* d_in, const int* in_sizes, int n_in,
                              void* d_out, int out_size, void* d_ws, size_t ws_size,
                              hipStream_t stream)
{
  const float* x    = (const float*)d_in[0];
  const int*   ei   = (const int*)d_in[1];
  const float* h0   = (const float*)d_in[2];
  const float* c0   = (const float*)d_in[3];
  const float* wih0f = (const float*)d_in[4];
  const float* whh0f = (const float*)d_in[5];
  const float* bih0f = (const float*)d_in[6];
  const float* bhh0f = (const float*)d_in[7];
  const float* wih0b = (const float*)d_in[8];
  const float* whh0b = (const float*)d_in[9];
  const float* bih0b = (const float*)d_in[10];
  const float* bhh0b = (const float*)d_in[11];
  const float* wih1f = (const float*)d_in[12];
  const float* whh1f = (const float*)d_in[13];
  const float* bih1f = (const float*)d_in[14];
  const float* bhh1f = (const float*)d_in[15];
  const float* wih1b = (const float*)d_in[16];
  const float* whh1b = (const float*)d_in[17];
  const float* bih1b = (const float*)d_in[18];
  const float* bhh1b = (const float*)d_in[19];
  const float* W1 = (const float*)d_in[20];
  const float* b1 = (const float*)d_in[21];
  const float* W2 = (const float*)d_in[22];
  const float* b2 = (const float*)d_in[23];

  char* ws = (char*)d_ws;
  int*   deg  = (int*)(ws + OFF_DEG);
  float* dinv = (float*)(ws + OFF_DINV);
  unsigned char* B0f8 = (unsigned char*)(ws + OFF_B0F);
  unsigned char* B0b8 = (unsigned char*)(ws + OFF_B0B);
  unsigned char* B1f8 = (unsigned char*)(ws + OFF_B1F);
  unsigned char* B1b8 = (unsigned char*)(ws + OFF_B1B);
  bf16* BW1 = (bf16*)(ws + OFF_BW1);
  bf16* BW2 = (bf16*)(ws + OFF_BW2);
  unsigned char* A0f8 = (unsigned char*)(ws + OFF_A0F);
  unsigned char* A0b8 = (unsigned char*)(ws + OFF_A0B);
  unsigned char* A1X8 = (unsigned char*)(ws + OFF_A1X);
  unsigned char* A1HF = (unsigned char*)(ws + OFF_A1HF);
  unsigned char* A1HB = (unsigned char*)(ws + OFF_A1HB);
  bf16* Afeat = (bf16*)(ws + OFF_AFEAT);
  float* xw1p  = (float*)(ws + OFF_XW1P);
  bf16*  xwt1b = (bf16*)(ws + OFF_XWT1B);
  float* adjf  = (float*)(ws + OFF_ADJF);
  bf16*  adjb  = (bf16*)(ws + OFF_ADJB);
  float* h1p   = (float*)(ws + OFF_H1P);
  bf16*  h1bf  = (bf16*)(ws + OFF_H1);
  float* xw2p  = (float*)(ws + OFF_XW2P);
  bf16*  xwt2b = (bf16*)(ws + OFF_XWT2B);
  float* o2p   = (float*)(ws + OFF_O2P);
  float* outp = (float*)d_out;

  // degree + norm
  hipMemsetAsync(deg, 0, (size_t)NN*4, stream);
  deg_count<<<dim3((EE+255)/256), 256, 0, stream>>>(ei + EE, deg);
  calc_dinv<<<dim3(15), 256, 0, stream>>>(deg, dinv);

  // weight packing: fp8 tiled (LSTM), bf16 (GCN)
  pack_B_8<<<dim3(NKT0*4, 16), 256, 0, stream>>>(wih0f, whh0f, B0f8, 588, NKT0);
  pack_B_8<<<dim3(NKT0*4, 16), 256, 0, stream>>>(wih0b, whh0b, B0b8, 588, NKT0);
  pack_B_8<<<dim3(NKT1*4, 16), 256, 0, stream>>>(wih1f, whh1f, B1f8, 1024, NKT1);
  pack_B_8<<<dim3(NKT1*4, 16), 256, 0, stream>>>(wih1b, whh1b, B1b8, 1024, NKT1);
  pack_BT<<<dim3(6, 512), 256, 0, stream>>>(W1, BW1, 512, 1408);
  pack_BT<<<dim3(2, 256), 256, 0, stream>>>(W2, BW2, 256, 512);

  // activations packing (fp8 tiled)
  pack_A0_8<<<dim3(NKT0*4, 29, 2), 256, 0, stream>>>(x, h0, A0f8, A0b8);
  pack_A1h_8<<<dim3(16, 29, 2), 256, 0, stream>>>(h0, A1HF, A1HB);

  // LSTM layer 0: MX-fp8, merged f+b, gate fused; writes x1 fp8 into shared A1X
  gemm_lstm8<0><<<dim3(32, 29), 256, 0, stream>>>(
      A0f8, A0f8, B0f8, c0,              bih0f, bhh0f,
      A0b8, A0b8, B0b8, c0 + (size_t)NH, bih0b, bhh0b,
      A1X8, NKT0, NKT0, 16);

  // feat: prot part (A0 dead; Afeat overlays it)
  pack_prot<<<dim3(2, MP), 256, 0, stream>>>(x, Afeat);

  // LSTM layer 1: MX-fp8, shared-x1 A + per-dir h0 tail; writes x_p/100 into feat
  gemm_lstm8<1><<<dim3(32, 29), 256, 0, stream>>>(
      A1X8, A1HF, B1f8, c0 + (size_t)2*NH, bih1f, bhh1f,
      A1X8, A1HB, B1b8, c0 + (size_t)3*NH, bih1b, bhh1b,
      Afeat, 8, NKT1, 16);

  // XW1^T = W1^T @ feat^T  split-K=4 (bf16)
  gemm_bt_sk<<<dim3(29, 4, 4), 256, 0, stream>>>(BW1, Afeat, xw1p, 1408, MP, 11);
  reduce_bf_pad<<<dim3(15, 512), 256, 0, stream>>>(xw1p, xwt1b, 4);

  // dense normalized adjacency (A1+xw1p dead)
  hipMemsetAsync(adjf, 0, (size_t)NN*KADJ*4, stream);
  adj_scatter<<<dim3((EE+NN+255)/256), 256, 0, stream>>>(ei, ei + EE, dinv, adjf);
  cvt_bf<<<dim3(15, MP), 256, 0, stream>>>(adjf, KADJ, adjb, NN, KADJ);

  // out1 = relu(Adj @ XW1 + b1) -> bf16, split-K=4
  gemm_bt_sk<<<dim3(4, 29, 4), 256, 0, stream>>>(adjb, xwt1b, h1p, KADJ, 512, 29);
  reduce_relu_bf<<<dim3(MP*512/256), 256, 0, stream>>>(h1p, b1, h1bf);

  // XW2^T = W2^T @ h1^T  split-K=4
  gemm_bt_sk<<<dim3(29, 2, 4), 256, 0, stream>>>(BW2, h1bf, xw2p, 512, MP, 4);
  reduce_bf_pad<<<dim3(15, 256), 256, 0, stream>>>(xw2p, xwt2b, 4);

  // out = Adj @ XW2 + b2, split-K=8
  gemm_bt_sk<<<dim3(2, 29, 8), 256, 0, stream>>>(adjb, xwt2b, o2p, KADJ, 256, 15);
  reduce_bias_out<<<dim3(3600), 256, 0, stream>>>(o2p, b2, outp);
}